// Round 6
// baseline (456.289 us; speedup 1.0000x reference)
//
#include <hip/hip_runtime.h>
#include <math.h>

// ---------------------------------------------------------------------------
// AGNN round 6: conv restructured to 8 lanes/edge x 8 edges/round (was 16x4).
//  - halves serial gather rounds per node (avg 5 -> 3), doubles gather MLP
//  - inactive slots predicated at the LOAD (no wasted gather traffic)
//  - reductions: dot {1,2,4}, cross-group {8,16,32}, epilogue-norm {1,2,4}
// Rest identical to round 4 (passing): XCD-partitioned scatter, dbuf+swizzled
// MFMA GEMM1 with fused normalize, normalized tables, GEMM2+log_softmax.
// ---------------------------------------------------------------------------

static inline int divup(int a, int b) { return (a + b - 1) / b; }

typedef __attribute__((ext_vector_type(8))) short short8;
typedef __attribute__((ext_vector_type(4))) float f32x4;
union U16 { uint4 u; short8 s; };

__device__ __forceinline__ unsigned bf16r(float f) {  // f32 -> bf16 bits, RNE
    unsigned u = __float_as_uint(f);
    return (u + 0x7FFFu + ((u >> 16) & 1u)) >> 16;
}
__device__ __forceinline__ unsigned pack2(float a, float b) {
    return bf16r(a) | (bf16r(b) << 16);
}
__device__ __forceinline__ float bflo(unsigned u) { return __uint_as_float(u << 16); }
__device__ __forceinline__ float bfhi(unsigned u) { return __uint_as_float(u & 0xFFFF0000u); }
__device__ __forceinline__ void unp8(uint4 u, float* v) {
    v[0] = bflo(u.x); v[1] = bfhi(u.x);
    v[2] = bflo(u.y); v[3] = bfhi(u.y);
    v[4] = bflo(u.z); v[5] = bfhi(u.z);
    v[6] = bflo(u.w); v[7] = bfhi(u.w);
}

// --- edge dtype detect / convert (+histogram fold) -------------------------
__global__ __launch_bounds__(64) void k_detect(const int* __restrict__ raw, int* flag) {
    int t = threadIdx.x;
    int v = raw[2 * t + 1];
    unsigned long long b = __ballot(v != 0);
    if (t == 0) *flag = (b == 0ULL) ? 1 : 0;  // 1 => int64 layout
}

__global__ __launch_bounds__(256) void k_cvt(const int* __restrict__ raw, int E,
                                             const int* __restrict__ flag,
                                             int* __restrict__ s32, int* __restrict__ d32,
                                             int* __restrict__ cnt) {
    int i = blockIdx.x * blockDim.x + threadIdx.x;
    if (i >= E) return;
    int s, d;
    if (*flag) {
        s = raw[2 * (size_t)i];
        d = raw[2 * ((size_t)E + i)];
    } else {
        s = raw[i];
        d = raw[(size_t)E + i];
    }
    s32[i] = s;
    d32[i] = d;
    atomicAdd(&cnt[d], 1);
}

// --- CSR scan (cnt + 1 self-loop per node) ---------------------------------
__global__ __launch_bounds__(1024) void k_scan1(const int* __restrict__ cnt, int N,
                                                int* __restrict__ rp, int* __restrict__ bsum) {
    __shared__ int sm[1024];
    int t = threadIdx.x;
    int i = blockIdx.x * 1024 + t;
    int v = (i < N) ? cnt[i] + 1 : 0;  // +1: self-loop
    sm[t] = v;
    __syncthreads();
#pragma unroll
    for (int off = 1; off < 1024; off <<= 1) {
        int u = (t >= off) ? sm[t - off] : 0;
        __syncthreads();
        sm[t] += u;
        __syncthreads();
    }
    if (i < N) rp[i] = sm[t] - v;  // exclusive
    if (t == 1023) bsum[blockIdx.x] = sm[t];
}

__global__ __launch_bounds__(64) void k_scan2(int* __restrict__ bsum, int nb) {
    if (threadIdx.x == 0) {
        int run = 0;
        for (int i = 0; i < nb; ++i) { int v = bsum[i]; bsum[i] = run; run += v; }
    }
}

__global__ __launch_bounds__(256) void k_scan3(int* __restrict__ rp, const int* __restrict__ bsum,
                                               int N, int Etot, int* __restrict__ cursor) {
    int i = blockIdx.x * blockDim.x + threadIdx.x;
    if (i < N) {
        int v = rp[i] + bsum[i >> 10];
        rp[i] = v;
        cursor[i] = v;
    } else if (i == N) {
        rp[N] = Etot;
    }
}

// --- XCD-partitioned scatter -----------------------------------------------
__global__ __launch_bounds__(256) void k_scatter(const int* __restrict__ s32,
                                                 const int* __restrict__ d32, int E, int N,
                                                 int* __restrict__ cursor,
                                                 int* __restrict__ esrc) {
    int b = blockIdx.x;
    int xcd = b & 7;
    int nstripe = gridDim.x >> 3;
    int stripe = b >> 3;
    int lo = (int)(((long long)xcd * N) >> 3);
    int hi = (int)(((long long)(xcd + 1) * N) >> 3);
    int Etot = E + N;
    for (int e = stripe * 256 + threadIdx.x; e < Etot; e += nstripe * 256) {
        int d = (e < E) ? d32[e] : (e - E);
        if (d < lo || d >= hi) continue;
        int s = (e < E) ? s32[e] : d;
        int pos = atomicAdd(&cursor[d], 1);
        esrc[pos] = s;
    }
}

// --- weight preconvert -----------------------------------------------------
__global__ __launch_bounds__(256) void k_cvtW1(const float* __restrict__ W1,
                                               unsigned short* __restrict__ W1t) {
    int i = blockIdx.x * 256 + threadIdx.x;
    if (i >= 512 * 128) return;
    int k = i >> 7, n = i & 127;
    W1t[n * 512 + k] = (unsigned short)bf16r(W1[i]);
}

__global__ __launch_bounds__(256) void k_cvtW2(const float* __restrict__ W2,
                                               unsigned short* __restrict__ W2t) {
    int i = blockIdx.x * 256 + threadIdx.x;
    if (i >= 128 * 64) return;
    int k = i >> 6, n = i & 63;
    W2t[n * 128 + k] = (unsigned short)bf16r(W2[i]);
}

// --- GEMM1: x_hat1/norm1 = normalize(relu(x @ W1 + b1)) --------------------
#define XS(row, off) ((off) ^ (((row) & 7) << 4))
__global__ __launch_bounds__(256) void k_gemm1(const float* __restrict__ x,
                                               const unsigned short* __restrict__ W1t,
                                               const float* __restrict__ b1, int N,
                                               unsigned short* __restrict__ xh1,
                                               float* __restrict__ n1) {
    __shared__ __align__(16) unsigned char lds[65536];
    const int tid = threadIdx.x;
    const int lane = tid & 63;
    const int lt = lane & 15, lg = lane >> 4;
    const int wid = tid >> 6;
    const int wr = wid >> 1, wc = wid & 1;
    const int row0 = blockIdx.x * 128;
    const int arow = tid >> 1, ahalf = tid & 1;

    f32x4 acc[4][4];
#pragma unroll
    for (int i = 0; i < 4; ++i)
#pragma unroll
        for (int j = 0; j < 4; ++j) acc[i][j] = (f32x4){0.f, 0.f, 0.f, 0.f};

    float4 av[8];
    uint4 bv[4];
    const int grow = row0 + arow;
    const bool aok = grow < N;

    auto issue = [&](int k0) {
        const float* xp = x + (size_t)grow * 512 + k0 + ahalf * 32;
#pragma unroll
        for (int i = 0; i < 8; ++i)
            av[i] = aok ? ((const float4*)xp)[i] : make_float4(0.f, 0.f, 0.f, 0.f);
        const unsigned short* wp = W1t + (size_t)arow * 512 + k0 + ahalf * 32;
#pragma unroll
        for (int i = 0; i < 4; ++i) bv[i] = ((const uint4*)wp)[i];
    };
    auto commit = [&](int buf) {
        unsigned char* ab = lds + buf * 32768 + arow * 128;
#pragma unroll
        for (int i = 0; i < 4; ++i) {
            uint4 q;
            q.x = pack2(av[2 * i].x, av[2 * i].y);
            q.y = pack2(av[2 * i].z, av[2 * i].w);
            q.z = pack2(av[2 * i + 1].x, av[2 * i + 1].y);
            q.w = pack2(av[2 * i + 1].z, av[2 * i + 1].w);
            *(uint4*)(ab + XS(arow, ahalf * 64 + i * 16)) = q;
        }
        unsigned char* bb = lds + 16384 + buf * 32768 + arow * 128;
#pragma unroll
        for (int i = 0; i < 4; ++i)
            *(uint4*)(bb + XS(arow, ahalf * 64 + i * 16)) = bv[i];
    };

    issue(0);
    commit(0);
    __syncthreads();

    for (int t = 0; t < 8; ++t) {
        const int cur = t & 1;
        if (t < 7) issue((t + 1) * 64);
        unsigned char* Acur = lds + cur * 32768;
        unsigned char* Bcur = lds + 16384 + cur * 32768;
#pragma unroll
        for (int sub = 0; sub < 2; ++sub) {
            U16 af[4], bf[4];
#pragma unroll
            for (int mi = 0; mi < 4; ++mi) {
                int r = wr * 64 + mi * 16 + lt;
                af[mi].u = *(const uint4*)(Acur + r * 128 + XS(r, sub * 64 + lg * 16));
            }
#pragma unroll
            for (int ni = 0; ni < 4; ++ni) {
                int r = wc * 64 + ni * 16 + lt;
                bf[ni].u = *(const uint4*)(Bcur + r * 128 + XS(r, sub * 64 + lg * 16));
            }
#pragma unroll
            for (int mi = 0; mi < 4; ++mi)
#pragma unroll
                for (int ni = 0; ni < 4; ++ni)
                    acc[mi][ni] = __builtin_amdgcn_mfma_f32_16x16x32_bf16(
                        af[mi].s, bf[ni].s, acc[mi][ni], 0, 0, 0);
        }
        if (t < 7) {
            commit(cur ^ 1);
            __syncthreads();
        }
    }

    // epilogue: bias+relu -> LDS rows -> norm -> x_hat bf16 + norm f32
    float bias[4];
#pragma unroll
    for (int ni = 0; ni < 4; ++ni) bias[ni] = b1[wc * 64 + ni * 16 + lt];
    float* sc = (float*)lds;  // 64 rows x 132 f32 = 33792B
#pragma unroll 1
    for (int c = 0; c < 2; ++c) {
        __syncthreads();
        if (wr == c) {
#pragma unroll
            for (int mi = 0; mi < 4; ++mi)
#pragma unroll
                for (int reg = 0; reg < 4; ++reg) {
                    int rl = mi * 16 + lg * 4 + reg;
#pragma unroll
                    for (int ni = 0; ni < 4; ++ni)
                        sc[rl * 132 + wc * 64 + ni * 16 + lt] =
                            fmaxf(acc[mi][ni][reg] + bias[ni], 0.f);
                }
        }
        __syncthreads();
        {
            int rl = tid >> 2, q = tid & 3;
            int gr = row0 + c * 64 + rl;
            const float* rowp = sc + rl * 132 + q * 32;
            float v[32];
#pragma unroll
            for (int i = 0; i < 8; ++i) {
                float4 f = ((const float4*)rowp)[i];
                v[4 * i] = f.x; v[4 * i + 1] = f.y; v[4 * i + 2] = f.z; v[4 * i + 3] = f.w;
            }
            float s2 = 0.f;
#pragma unroll
            for (int i = 0; i < 32; ++i) s2 += v[i] * v[i];
            s2 += __shfl_xor(s2, 1, 64);
            s2 += __shfl_xor(s2, 2, 64);
            float nrm = sqrtf(s2);
            float rn = 1.0f / fmaxf(nrm, 1e-12f);
            if (gr < N) {
                uint4 o[4];
                unsigned* op = (unsigned*)o;
#pragma unroll
                for (int i = 0; i < 16; ++i)
                    op[i] = pack2(v[2 * i] * rn, v[2 * i + 1] * rn);
                uint4* dst = (uint4*)(xh1 + (size_t)gr * 128 + q * 32);
                dst[0] = o[0];
                dst[1] = o[1];
                dst[2] = o[2];
                dst[3] = o[3];
                if (q == 0) n1[gr] = nrm;
            }
        }
    }
}

// --- AGNN conv: wave per dst node, 8 lanes/edge, 8 edges/round -------------
// lane t = lane&7 covers dims [16t,16t+16); group g = lane>>3 = edge slot.
// dot reduce {1,2,4}; cross-group combine {8,16,32}; norm-s2 reduce {1,2,4}.
__global__ __launch_bounds__(256) void k_conv(const unsigned short* __restrict__ xh,
                                              const float* __restrict__ nrmt,
                                              const int* __restrict__ rp,
                                              const int* __restrict__ esrc, int N,
                                              const float* __restrict__ betap,
                                              unsigned short* __restrict__ outh,
                                              float* __restrict__ outn) {
    int node = (blockIdx.x * blockDim.x + threadIdx.x) >> 6;
    if (node >= N) return;
    int lane = threadIdx.x & 63;
    int t = lane & 7, g = lane >> 3;
    float beta = betap ? *betap : 1.0f;

    const uint4* drp = (const uint4*)&xh[(size_t)node * 128 + 16 * t];
    uint4 dd0 = drp[0], dd1 = drp[1];
    float hd[16];
    unp8(dd0, hd);
    unp8(dd1, hd + 8);

    int e0 = rp[node], e1 = rp[node + 1];
    float acc[16];
#pragma unroll
    for (int j = 0; j < 16; ++j) acc[j] = 0.f;
    float ssum = 0.f;

    for (int eb = e0; eb < e1; eb += 8) {
        int e = eb + g;
        bool act = e < e1;
        float v[16];
        float ns = 0.f;
        float p = 0.f;
        if (act) {
            int s = esrc[e];
            ns = nrmt[s];
            const uint4* srp = (const uint4*)&xh[(size_t)s * 128 + 16 * t];
            uint4 s0 = srp[0], s1 = srp[1];
            unp8(s0, v);
            unp8(s1, v + 8);
#pragma unroll
            for (int j = 0; j < 16; ++j) p += v[j] * hd[j];
        } else {
#pragma unroll
            for (int j = 0; j < 16; ++j) v[j] = 0.f;
        }
        p += __shfl_xor(p, 1, 64);
        p += __shfl_xor(p, 2, 64);
        p += __shfl_xor(p, 4, 64);
        float w = act ? __expf(p * beta) : 0.f;
        float wn = w * ns;
        ssum += w;
#pragma unroll
        for (int j = 0; j < 16; ++j) acc[j] += wn * v[j];
    }
#pragma unroll
    for (int j = 0; j < 16; ++j) {
        acc[j] += __shfl_xor(acc[j], 8, 64);
        acc[j] += __shfl_xor(acc[j], 16, 64);
        acc[j] += __shfl_xor(acc[j], 32, 64);
    }
    ssum += __shfl_xor(ssum, 8, 64);
    ssum += __shfl_xor(ssum, 16, 64);
    ssum += __shfl_xor(ssum, 32, 64);
    float r = 1.0f / ssum;

    if (outn == nullptr) {
        if (g == 0) {
            uint4 q0, q1;
            q0.x = pack2(acc[0] * r, acc[1] * r);
            q0.y = pack2(acc[2] * r, acc[3] * r);
            q0.z = pack2(acc[4] * r, acc[5] * r);
            q0.w = pack2(acc[6] * r, acc[7] * r);
            q1.x = pack2(acc[8] * r, acc[9] * r);
            q1.y = pack2(acc[10] * r, acc[11] * r);
            q1.z = pack2(acc[12] * r, acc[13] * r);
            q1.w = pack2(acc[14] * r, acc[15] * r);
            uint4* dst = (uint4*)&outh[(size_t)node * 128 + 16 * t];
            dst[0] = q0;
            dst[1] = q1;
        }
    } else {
        float o[16];
        float s2 = 0.f;
#pragma unroll
        for (int j = 0; j < 16; ++j) { o[j] = acc[j] * r; s2 += o[j] * o[j]; }
        s2 += __shfl_xor(s2, 1, 64);
        s2 += __shfl_xor(s2, 2, 64);
        s2 += __shfl_xor(s2, 4, 64);
        float nn = sqrtf(s2);
        float rn = 1.0f / fmaxf(nn, 1e-12f);
        if (g == 0) {
            uint4 q0, q1;
            q0.x = pack2(o[0] * rn, o[1] * rn);
            q0.y = pack2(o[2] * rn, o[3] * rn);
            q0.z = pack2(o[4] * rn, o[5] * rn);
            q0.w = pack2(o[6] * rn, o[7] * rn);
            q1.x = pack2(o[8] * rn, o[9] * rn);
            q1.y = pack2(o[10] * rn, o[11] * rn);
            q1.z = pack2(o[12] * rn, o[13] * rn);
            q1.w = pack2(o[14] * rn, o[15] * rn);
            uint4* dst = (uint4*)&outh[(size_t)node * 128 + 16 * t];
            dst[0] = q0;
            dst[1] = q1;
            if (t == 0) outn[node] = nn;
        }
    }
}

// --- GEMM2 (MFMA) + fused log_softmax --------------------------------------
#define G2_ASTRIDE 272
__global__ __launch_bounds__(256) void k_gemm2(const unsigned short* __restrict__ h,
                                               const unsigned short* __restrict__ W2t,
                                               const float* __restrict__ b2, int N,
                                               float* __restrict__ out) {
    __shared__ __align__(16) unsigned char As[128 * G2_ASTRIDE];
    __shared__ __align__(16) unsigned char Bs[64 * G2_ASTRIDE];
    const int tid = threadIdx.x;
    const int lane = tid & 63;
    const int lt = lane & 15, lg = lane >> 4;
    const int wid = tid >> 6;
    const int row0 = blockIdx.x * 128;

    {
        int arow = tid >> 1, ahalf = tid & 1;
        const uint4* src = (const uint4*)(h + (size_t)(row0 + arow) * 128 + ahalf * 64);
        unsigned char* ab = As + arow * G2_ASTRIDE + ahalf * 128;
#pragma unroll
        for (int i = 0; i < 8; ++i) ((uint4*)ab)[i] = src[i];
        int brow = tid >> 2, bq = tid & 3;
        const uint4* bs = (const uint4*)(W2t + (size_t)brow * 128 + bq * 32);
        unsigned char* bb = Bs + brow * G2_ASTRIDE + bq * 64;
#pragma unroll
        for (int i = 0; i < 4; ++i) ((uint4*)bb)[i] = bs[i];
    }
    __syncthreads();

    f32x4 acc[2][4];
#pragma unroll
    for (int i = 0; i < 2; ++i)
#pragma unroll
        for (int j = 0; j < 4; ++j) acc[i][j] = (f32x4){0.f, 0.f, 0.f, 0.f};

#pragma unroll
    for (int sub = 0; sub < 4; ++sub) {
        U16 af[2], bf[4];
#pragma unroll
        for (int mi = 0; mi < 2; ++mi)
            af[mi].u = *(const uint4*)(As + (wid * 32 + mi * 16 + lt) * G2_ASTRIDE + sub * 64 + lg * 16);
#pragma unroll
        for (int ni = 0; ni < 4; ++ni)
            bf[ni].u = *(const uint4*)(Bs + (ni * 16 + lt) * G2_ASTRIDE + sub * 64 + lg * 16);
#pragma unroll
        for (int mi = 0; mi < 2; ++mi)
#pragma unroll
            for (int ni = 0; ni < 4; ++ni)
                acc[mi][ni] = __builtin_amdgcn_mfma_f32_16x16x32_bf16(
                    af[mi].s, bf[ni].s, acc[mi][ni], 0, 0, 0);
    }

    float bias[4];
#pragma unroll
    for (int ni = 0; ni < 4; ++ni) bias[ni] = b2[ni * 16 + lt];

#pragma unroll
    for (int mi = 0; mi < 2; ++mi) {
#pragma unroll
        for (int reg = 0; reg < 4; ++reg) {
            int row = row0 + wid * 32 + mi * 16 + lg * 4 + reg;
            if (row < N) {
                float v[4];
#pragma unroll
                for (int ni = 0; ni < 4; ++ni) v[ni] = acc[mi][ni][reg] + bias[ni];
                float m = fmaxf(fmaxf(v[0], v[1]), fmaxf(v[2], v[3]));
                m = fmaxf(m, __shfl_xor(m, 1, 64));
                m = fmaxf(m, __shfl_xor(m, 2, 64));
                m = fmaxf(m, __shfl_xor(m, 4, 64));
                m = fmaxf(m, __shfl_xor(m, 8, 64));
                float s = __expf(v[0] - m) + __expf(v[1] - m) +
                          __expf(v[2] - m) + __expf(v[3] - m);
                s += __shfl_xor(s, 1, 64);
                s += __shfl_xor(s, 2, 64);
                s += __shfl_xor(s, 4, 64);
                s += __shfl_xor(s, 8, 64);
                float lg2 = logf(s);
#pragma unroll
                for (int ni = 0; ni < 4; ++ni)
                    out[(size_t)row * 64 + ni * 16 + lt] = v[ni] - m - lg2;
            }
        }
    }
}

// ---------------------------------------------------------------------------
extern "C" void kernel_launch(void* const* d_in, const int* in_sizes, int n_in,
                              void* d_out, int out_size, void* d_ws, size_t ws_size,
                              hipStream_t stream) {
    const float* x     = (const float*)d_in[0];
    const int*   ei    = (const int*)d_in[1];
    const float* W1    = (const float*)d_in[2];
    const float* b1    = (const float*)d_in[3];
    const float* beta2 = (const float*)d_in[4];
    const float* W2    = (const float*)d_in[5];
    const float* b2    = (const float*)d_in[6];
    float* out = (float*)d_out;

    const int N = in_sizes[0] / 512;
    const int E = in_sizes[1] / 2;
    const int Etot = E + N;

    char* ws = (char*)d_ws;
    size_t off = 0;
    auto alloc = [&](size_t bytes) -> void* {
        void* p = ws + off;
        off = (off + bytes + 511) & ~(size_t)511;
        return p;
    };
    unsigned short* t1 = (unsigned short*)alloc((size_t)N * 128 * 2);  // x_hat1 / h3
    unsigned short* t2 = (unsigned short*)alloc((size_t)N * 128 * 2);  // x_hat2
    float* n1   = (float*)alloc((size_t)N * 4);
    float* n2   = (float*)alloc((size_t)N * 4);
    int* cnt    = (int*)alloc((size_t)N * 4);
    int* rp     = (int*)alloc((size_t)(N + 1) * 4);
    int* cursor = (int*)alloc((size_t)N * 4);
    int* bsum   = (int*)alloc(4096);
    int* flag   = (int*)alloc(512);
    unsigned short* W1t = (unsigned short*)alloc(512 * 128 * 2);
    unsigned short* W2t = (unsigned short*)alloc(128 * 64 * 2);
    int* s32    = (int*)alloc((size_t)E * 4);
    int* d32    = (int*)alloc((size_t)E * 4);
    int* esrc   = (int*)alloc((size_t)Etot * 4);
    (void)ws_size; (void)n_in; (void)out_size;

    (void)hipMemsetAsync(cnt, 0, (size_t)N * 4, stream);

    k_detect<<<1, 64, 0, stream>>>(ei, flag);
    k_cvt<<<divup(E, 256), 256, 0, stream>>>(ei, E, flag, s32, d32, cnt);
    int nb = divup(N, 1024);
    k_scan1<<<nb, 1024, 0, stream>>>(cnt, N, rp, bsum);
    k_scan2<<<1, 64, 0, stream>>>(bsum, nb);
    k_scan3<<<divup(N + 1, 256), 256, 0, stream>>>(rp, bsum, N, Etot, cursor);
    k_scatter<<<2048, 256, 0, stream>>>(s32, d32, E, N, cursor, esrc);

    k_cvtW1<<<divup(512 * 128, 256), 256, 0, stream>>>(W1, W1t);
    k_cvtW2<<<divup(128 * 64, 256), 256, 0, stream>>>(W2, W2t);

    k_gemm1<<<divup(N, 128), 256, 0, stream>>>(x, W1t, b1, N, t1, n1);
    k_conv<<<divup(N, 4), 256, 0, stream>>>(t1, n1, rp, esrc, N, nullptr, t2, n2);
    k_conv<<<divup(N, 4), 256, 0, stream>>>(t2, n2, rp, esrc, N, beta2, t1, nullptr);
    k_gemm2<<<divup(N, 128), 256, 0, stream>>>(t1, W2t, b2, N, out);
}

// Round 7
// 453.689 us; speedup vs baseline: 1.0057x; 1.0057x over previous
//
#include <hip/hip_runtime.h>
#include <math.h>

// ---------------------------------------------------------------------------
// AGNN round 7:
//  - conv REVERTED to round-4 16 lanes/edge x 4 edges (r6's 8x8 A/B-regressed)
//  - gemm1: single-buffered LDS (34KB, was 64KB dbuf -> 2 blk/CU cap) with
//    issue-early schedule (loads for t+1 in flight during compute of t)
//  - rest identical to round 4/5 passing config
// ---------------------------------------------------------------------------

static inline int divup(int a, int b) { return (a + b - 1) / b; }

typedef __attribute__((ext_vector_type(8))) short short8;
typedef __attribute__((ext_vector_type(4))) float f32x4;
union U16 { uint4 u; short8 s; };

__device__ __forceinline__ unsigned bf16r(float f) {  // f32 -> bf16 bits, RNE
    unsigned u = __float_as_uint(f);
    return (u + 0x7FFFu + ((u >> 16) & 1u)) >> 16;
}
__device__ __forceinline__ unsigned pack2(float a, float b) {
    return bf16r(a) | (bf16r(b) << 16);
}
__device__ __forceinline__ float bflo(unsigned u) { return __uint_as_float(u << 16); }
__device__ __forceinline__ float bfhi(unsigned u) { return __uint_as_float(u & 0xFFFF0000u); }

// --- edge dtype detect / convert (+histogram fold) -------------------------
__global__ __launch_bounds__(64) void k_detect(const int* __restrict__ raw, int* flag) {
    int t = threadIdx.x;
    int v = raw[2 * t + 1];
    unsigned long long b = __ballot(v != 0);
    if (t == 0) *flag = (b == 0ULL) ? 1 : 0;  // 1 => int64 layout
}

__global__ __launch_bounds__(256) void k_cvt(const int* __restrict__ raw, int E,
                                             const int* __restrict__ flag,
                                             int* __restrict__ s32, int* __restrict__ d32,
                                             int* __restrict__ cnt) {
    int i = blockIdx.x * blockDim.x + threadIdx.x;
    if (i >= E) return;
    int s, d;
    if (*flag) {
        s = raw[2 * (size_t)i];
        d = raw[2 * ((size_t)E + i)];
    } else {
        s = raw[i];
        d = raw[(size_t)E + i];
    }
    s32[i] = s;
    d32[i] = d;
    atomicAdd(&cnt[d], 1);
}

// --- CSR scan (cnt + 1 self-loop per node) ---------------------------------
__global__ __launch_bounds__(1024) void k_scan1(const int* __restrict__ cnt, int N,
                                                int* __restrict__ rp, int* __restrict__ bsum) {
    __shared__ int sm[1024];
    int t = threadIdx.x;
    int i = blockIdx.x * 1024 + t;
    int v = (i < N) ? cnt[i] + 1 : 0;  // +1: self-loop
    sm[t] = v;
    __syncthreads();
#pragma unroll
    for (int off = 1; off < 1024; off <<= 1) {
        int u = (t >= off) ? sm[t - off] : 0;
        __syncthreads();
        sm[t] += u;
        __syncthreads();
    }
    if (i < N) rp[i] = sm[t] - v;  // exclusive
    if (t == 1023) bsum[blockIdx.x] = sm[t];
}

__global__ __launch_bounds__(64) void k_scan2(int* __restrict__ bsum, int nb) {
    if (threadIdx.x == 0) {
        int run = 0;
        for (int i = 0; i < nb; ++i) { int v = bsum[i]; bsum[i] = run; run += v; }
    }
}

__global__ __launch_bounds__(256) void k_scan3(int* __restrict__ rp, const int* __restrict__ bsum,
                                               int N, int Etot, int* __restrict__ cursor) {
    int i = blockIdx.x * blockDim.x + threadIdx.x;
    if (i < N) {
        int v = rp[i] + bsum[i >> 10];
        rp[i] = v;
        cursor[i] = v;
    } else if (i == N) {
        rp[N] = Etot;
    }
}

// --- XCD-partitioned scatter -----------------------------------------------
__global__ __launch_bounds__(256) void k_scatter(const int* __restrict__ s32,
                                                 const int* __restrict__ d32, int E, int N,
                                                 int* __restrict__ cursor,
                                                 int* __restrict__ esrc) {
    int b = blockIdx.x;
    int xcd = b & 7;
    int nstripe = gridDim.x >> 3;
    int stripe = b >> 3;
    int lo = (int)(((long long)xcd * N) >> 3);
    int hi = (int)(((long long)(xcd + 1) * N) >> 3);
    int Etot = E + N;
    for (int e = stripe * 256 + threadIdx.x; e < Etot; e += nstripe * 256) {
        int d = (e < E) ? d32[e] : (e - E);
        if (d < lo || d >= hi) continue;
        int s = (e < E) ? s32[e] : d;
        int pos = atomicAdd(&cursor[d], 1);
        esrc[pos] = s;
    }
}

// --- weight preconvert -----------------------------------------------------
__global__ __launch_bounds__(256) void k_cvtW1(const float* __restrict__ W1,
                                               unsigned short* __restrict__ W1t) {
    int i = blockIdx.x * 256 + threadIdx.x;
    if (i >= 512 * 128) return;
    int k = i >> 7, n = i & 127;
    W1t[n * 512 + k] = (unsigned short)bf16r(W1[i]);
}

__global__ __launch_bounds__(256) void k_cvtW2(const float* __restrict__ W2,
                                               unsigned short* __restrict__ W2t) {
    int i = blockIdx.x * 256 + threadIdx.x;
    if (i >= 128 * 64) return;
    int k = i >> 6, n = i & 63;
    W2t[n * 128 + k] = (unsigned short)bf16r(W2[i]);
}

// --- GEMM1: x_hat1/norm1 = normalize(relu(x @ W1 + b1)) --------------------
// 128x128 tile, BK=64, SINGLE-buffered swizzled LDS (34KB -> 4 blk/CU),
// issue-early: t+1 global loads in regs while computing t from LDS.
#define XS(row, off) ((off) ^ (((row) & 7) << 4))
__global__ __launch_bounds__(256) void k_gemm1(const float* __restrict__ x,
                                               const unsigned short* __restrict__ W1t,
                                               const float* __restrict__ b1, int N,
                                               unsigned short* __restrict__ xh1,
                                               float* __restrict__ n1) {
    __shared__ __align__(16) unsigned char lds[33792];  // 32K stage / 33792 epi
    const int tid = threadIdx.x;
    const int lane = tid & 63;
    const int lt = lane & 15, lg = lane >> 4;
    const int wid = tid >> 6;
    const int wr = wid >> 1, wc = wid & 1;
    const int row0 = blockIdx.x * 128;
    const int arow = tid >> 1, ahalf = tid & 1;

    f32x4 acc[4][4];
#pragma unroll
    for (int i = 0; i < 4; ++i)
#pragma unroll
        for (int j = 0; j < 4; ++j) acc[i][j] = (f32x4){0.f, 0.f, 0.f, 0.f};

    float4 av[8];
    uint4 bv[4];
    const int grow = row0 + arow;
    const bool aok = grow < N;

    auto issue = [&](int k0) {
        const float* xp = x + (size_t)grow * 512 + k0 + ahalf * 32;
#pragma unroll
        for (int i = 0; i < 8; ++i)
            av[i] = aok ? ((const float4*)xp)[i] : make_float4(0.f, 0.f, 0.f, 0.f);
        const unsigned short* wp = W1t + (size_t)arow * 512 + k0 + ahalf * 32;
#pragma unroll
        for (int i = 0; i < 4; ++i) bv[i] = ((const uint4*)wp)[i];
    };
    auto commit = [&]() {
        unsigned char* ab = lds + arow * 128;
#pragma unroll
        for (int i = 0; i < 4; ++i) {
            uint4 q;
            q.x = pack2(av[2 * i].x, av[2 * i].y);
            q.y = pack2(av[2 * i].z, av[2 * i].w);
            q.z = pack2(av[2 * i + 1].x, av[2 * i + 1].y);
            q.w = pack2(av[2 * i + 1].z, av[2 * i + 1].w);
            *(uint4*)(ab + XS(arow, ahalf * 64 + i * 16)) = q;
        }
        unsigned char* bb = lds + 16384 + arow * 128;
#pragma unroll
        for (int i = 0; i < 4; ++i)
            *(uint4*)(bb + XS(arow, ahalf * 64 + i * 16)) = bv[i];
    };

    issue(0);
    commit();
    __syncthreads();

    for (int t = 0; t < 8; ++t) {
        if (t < 7) issue((t + 1) * 64);  // loads fly during compute below
#pragma unroll
        for (int sub = 0; sub < 2; ++sub) {
            U16 af[4], bf[4];
#pragma unroll
            for (int mi = 0; mi < 4; ++mi) {
                int r = wr * 64 + mi * 16 + lt;
                af[mi].u = *(const uint4*)(lds + r * 128 + XS(r, sub * 64 + lg * 16));
            }
#pragma unroll
            for (int ni = 0; ni < 4; ++ni) {
                int r = wc * 64 + ni * 16 + lt;
                bf[ni].u = *(const uint4*)(lds + 16384 + r * 128 + XS(r, sub * 64 + lg * 16));
            }
#pragma unroll
            for (int mi = 0; mi < 4; ++mi)
#pragma unroll
                for (int ni = 0; ni < 4; ++ni)
                    acc[mi][ni] = __builtin_amdgcn_mfma_f32_16x16x32_bf16(
                        af[mi].s, bf[ni].s, acc[mi][ni], 0, 0, 0);
        }
        __syncthreads();  // all LDS reads of tile t done
        if (t < 7) {
            commit();
            __syncthreads();
        }
    }

    // epilogue: bias+relu -> LDS rows -> norm -> x_hat bf16 + norm f32
    float bias[4];
#pragma unroll
    for (int ni = 0; ni < 4; ++ni) bias[ni] = b1[wc * 64 + ni * 16 + lt];
    float* sc = (float*)lds;  // 64 rows x 132 f32 = 33792B
#pragma unroll 1
    for (int c = 0; c < 2; ++c) {
        __syncthreads();
        if (wr == c) {
#pragma unroll
            for (int mi = 0; mi < 4; ++mi)
#pragma unroll
                for (int reg = 0; reg < 4; ++reg) {
                    int rl = mi * 16 + lg * 4 + reg;
#pragma unroll
                    for (int ni = 0; ni < 4; ++ni)
                        sc[rl * 132 + wc * 64 + ni * 16 + lt] =
                            fmaxf(acc[mi][ni][reg] + bias[ni], 0.f);
                }
        }
        __syncthreads();
        {
            int rl = tid >> 2, q = tid & 3;
            int gr = row0 + c * 64 + rl;
            const float* rowp = sc + rl * 132 + q * 32;
            float v[32];
#pragma unroll
            for (int i = 0; i < 8; ++i) {
                float4 f = ((const float4*)rowp)[i];
                v[4 * i] = f.x; v[4 * i + 1] = f.y; v[4 * i + 2] = f.z; v[4 * i + 3] = f.w;
            }
            float s2 = 0.f;
#pragma unroll
            for (int i = 0; i < 32; ++i) s2 += v[i] * v[i];
            s2 += __shfl_xor(s2, 1, 64);
            s2 += __shfl_xor(s2, 2, 64);
            float nrm = sqrtf(s2);
            float rn = 1.0f / fmaxf(nrm, 1e-12f);
            if (gr < N) {
                uint4 o[4];
                unsigned* op = (unsigned*)o;
#pragma unroll
                for (int i = 0; i < 16; ++i)
                    op[i] = pack2(v[2 * i] * rn, v[2 * i + 1] * rn);
                uint4* dst = (uint4*)(xh1 + (size_t)gr * 128 + q * 32);
                dst[0] = o[0];
                dst[1] = o[1];
                dst[2] = o[2];
                dst[3] = o[3];
                if (q == 0) n1[gr] = nrm;
            }
        }
    }
}

// --- AGNN conv (r4 structure): wave/node, 16 lanes/edge, 4 edges/round -----
__global__ __launch_bounds__(256) void k_conv(const unsigned short* __restrict__ xh,
                                              const float* __restrict__ nrmt,
                                              const int* __restrict__ rp,
                                              const int* __restrict__ esrc, int N,
                                              const float* __restrict__ betap,
                                              unsigned short* __restrict__ outh,
                                              float* __restrict__ outn) {
    int node = (blockIdx.x * blockDim.x + threadIdx.x) >> 6;
    if (node >= N) return;
    int lane = threadIdx.x & 63;
    int t = lane & 15, g = lane >> 4;
    float beta = betap ? *betap : 1.0f;

    uint4 hdu = *(const uint4*)&xh[(size_t)node * 128 + 8 * t];
    float hd[8];
    hd[0] = bflo(hdu.x); hd[1] = bfhi(hdu.x);
    hd[2] = bflo(hdu.y); hd[3] = bfhi(hdu.y);
    hd[4] = bflo(hdu.z); hd[5] = bfhi(hdu.z);
    hd[6] = bflo(hdu.w); hd[7] = bfhi(hdu.w);

    int e0 = rp[node], e1 = rp[node + 1];
    float acc[8] = {0.f, 0.f, 0.f, 0.f, 0.f, 0.f, 0.f, 0.f};
    float ssum = 0.f;

    for (int eb = e0; eb < e1; eb += 4) {
        int e = eb + g;
        int ee = (e < e1) ? e : e0;
        int s = esrc[ee];
        float ns = nrmt[s];
        uint4 hu = *(const uint4*)&xh[(size_t)s * 128 + 8 * t];
        float v[8];
        v[0] = bflo(hu.x); v[1] = bfhi(hu.x);
        v[2] = bflo(hu.y); v[3] = bfhi(hu.y);
        v[4] = bflo(hu.z); v[5] = bfhi(hu.z);
        v[6] = bflo(hu.w); v[7] = bfhi(hu.w);
        float p = 0.f;
#pragma unroll
        for (int j = 0; j < 8; ++j) p += v[j] * hd[j];
        p += __shfl_xor(p, 1, 64);
        p += __shfl_xor(p, 2, 64);
        p += __shfl_xor(p, 4, 64);
        p += __shfl_xor(p, 8, 64);
        float w = (e < e1) ? __expf(p * beta) : 0.f;
        float wn = w * ns;
        ssum += w;
#pragma unroll
        for (int j = 0; j < 8; ++j) acc[j] += wn * v[j];
    }
#pragma unroll
    for (int j = 0; j < 8; ++j) {
        acc[j] += __shfl_xor(acc[j], 16, 64);
        acc[j] += __shfl_xor(acc[j], 32, 64);
    }
    ssum += __shfl_xor(ssum, 16, 64);
    ssum += __shfl_xor(ssum, 32, 64);
    float r = 1.0f / ssum;

    if (outn == nullptr) {
        if (g == 0) {
            uint4 q;
            q.x = pack2(acc[0] * r, acc[1] * r);
            q.y = pack2(acc[2] * r, acc[3] * r);
            q.z = pack2(acc[4] * r, acc[5] * r);
            q.w = pack2(acc[6] * r, acc[7] * r);
            *(uint4*)&outh[(size_t)node * 128 + 8 * t] = q;
        }
    } else {
        float o[8];
        float s2 = 0.f;
#pragma unroll
        for (int j = 0; j < 8; ++j) { o[j] = acc[j] * r; s2 += o[j] * o[j]; }
        s2 += __shfl_xor(s2, 1, 64);
        s2 += __shfl_xor(s2, 2, 64);
        s2 += __shfl_xor(s2, 4, 64);
        s2 += __shfl_xor(s2, 8, 64);
        float nn = sqrtf(s2);
        float rn = 1.0f / fmaxf(nn, 1e-12f);
        if (g == 0) {
            uint4 q;
            q.x = pack2(o[0] * rn, o[1] * rn);
            q.y = pack2(o[2] * rn, o[3] * rn);
            q.z = pack2(o[4] * rn, o[5] * rn);
            q.w = pack2(o[6] * rn, o[7] * rn);
            *(uint4*)&outh[(size_t)node * 128 + 8 * t] = q;
            if (t == 0) outn[node] = nn;
        }
    }
}

// --- GEMM2 (MFMA) + fused log_softmax --------------------------------------
#define G2_ASTRIDE 272
__global__ __launch_bounds__(256) void k_gemm2(const unsigned short* __restrict__ h,
                                               const unsigned short* __restrict__ W2t,
                                               const float* __restrict__ b2, int N,
                                               float* __restrict__ out) {
    __shared__ __align__(16) unsigned char As[128 * G2_ASTRIDE];
    __shared__ __align__(16) unsigned char Bs[64 * G2_ASTRIDE];
    const int tid = threadIdx.x;
    const int lane = tid & 63;
    const int lt = lane & 15, lg = lane >> 4;
    const int wid = tid >> 6;
    const int row0 = blockIdx.x * 128;

    {
        int arow = tid >> 1, ahalf = tid & 1;
        const uint4* src = (const uint4*)(h + (size_t)(row0 + arow) * 128 + ahalf * 64);
        unsigned char* ab = As + arow * G2_ASTRIDE + ahalf * 128;
#pragma unroll
        for (int i = 0; i < 8; ++i) ((uint4*)ab)[i] = src[i];
        int brow = tid >> 2, bq = tid & 3;
        const uint4* bs = (const uint4*)(W2t + (size_t)brow * 128 + bq * 32);
        unsigned char* bb = Bs + brow * G2_ASTRIDE + bq * 64;
#pragma unroll
        for (int i = 0; i < 4; ++i) ((uint4*)bb)[i] = bs[i];
    }
    __syncthreads();

    f32x4 acc[2][4];
#pragma unroll
    for (int i = 0; i < 2; ++i)
#pragma unroll
        for (int j = 0; j < 4; ++j) acc[i][j] = (f32x4){0.f, 0.f, 0.f, 0.f};

#pragma unroll
    for (int sub = 0; sub < 4; ++sub) {
        U16 af[2], bf[4];
#pragma unroll
        for (int mi = 0; mi < 2; ++mi)
            af[mi].u = *(const uint4*)(As + (wid * 32 + mi * 16 + lt) * G2_ASTRIDE + sub * 64 + lg * 16);
#pragma unroll
        for (int ni = 0; ni < 4; ++ni)
            bf[ni].u = *(const uint4*)(Bs + (ni * 16 + lt) * G2_ASTRIDE + sub * 64 + lg * 16);
#pragma unroll
        for (int mi = 0; mi < 2; ++mi)
#pragma unroll
            for (int ni = 0; ni < 4; ++ni)
                acc[mi][ni] = __builtin_amdgcn_mfma_f32_16x16x32_bf16(
                    af[mi].s, bf[ni].s, acc[mi][ni], 0, 0, 0);
    }

    float bias[4];
#pragma unroll
    for (int ni = 0; ni < 4; ++ni) bias[ni] = b2[ni * 16 + lt];

#pragma unroll
    for (int mi = 0; mi < 2; ++mi) {
#pragma unroll
        for (int reg = 0; reg < 4; ++reg) {
            int row = row0 + wid * 32 + mi * 16 + lg * 4 + reg;
            if (row < N) {
                float v[4];
#pragma unroll
                for (int ni = 0; ni < 4; ++ni) v[ni] = acc[mi][ni][reg] + bias[ni];
                float m = fmaxf(fmaxf(v[0], v[1]), fmaxf(v[2], v[3]));
                m = fmaxf(m, __shfl_xor(m, 1, 64));
                m = fmaxf(m, __shfl_xor(m, 2, 64));
                m = fmaxf(m, __shfl_xor(m, 4, 64));
                m = fmaxf(m, __shfl_xor(m, 8, 64));
                float s = __expf(v[0] - m) + __expf(v[1] - m) +
                          __expf(v[2] - m) + __expf(v[3] - m);
                s += __shfl_xor(s, 1, 64);
                s += __shfl_xor(s, 2, 64);
                s += __shfl_xor(s, 4, 64);
                s += __shfl_xor(s, 8, 64);
                float lg2 = logf(s);
#pragma unroll
                for (int ni = 0; ni < 4; ++ni)
                    out[(size_t)row * 64 + ni * 16 + lt] = v[ni] - m - lg2;
            }
        }
    }
}

// ---------------------------------------------------------------------------
extern "C" void kernel_launch(void* const* d_in, const int* in_sizes, int n_in,
                              void* d_out, int out_size, void* d_ws, size_t ws_size,
                              hipStream_t stream) {
    const float* x     = (const float*)d_in[0];
    const int*   ei    = (const int*)d_in[1];
    const float* W1    = (const float*)d_in[2];
    const float* b1    = (const float*)d_in[3];
    const float* beta2 = (const float*)d_in[4];
    const float* W2    = (const float*)d_in[5];
    const float* b2    = (const float*)d_in[6];
    float* out = (float*)d_out;

    const int N = in_sizes[0] / 512;
    const int E = in_sizes[1] / 2;
    const int Etot = E + N;

    char* ws = (char*)d_ws;
    size_t off = 0;
    auto alloc = [&](size_t bytes) -> void* {
        void* p = ws + off;
        off = (off + bytes + 511) & ~(size_t)511;
        return p;
    };
    unsigned short* t1 = (unsigned short*)alloc((size_t)N * 128 * 2);  // x_hat1 / h3
    unsigned short* t2 = (unsigned short*)alloc((size_t)N * 128 * 2);  // x_hat2
    float* n1   = (float*)alloc((size_t)N * 4);
    float* n2   = (float*)alloc((size_t)N * 4);
    int* cnt    = (int*)alloc((size_t)N * 4);
    int* rp     = (int*)alloc((size_t)(N + 1) * 4);
    int* cursor = (int*)alloc((size_t)N * 4);
    int* bsum   = (int*)alloc(4096);
    int* flag   = (int*)alloc(512);
    unsigned short* W1t = (unsigned short*)alloc(512 * 128 * 2);
    unsigned short* W2t = (unsigned short*)alloc(128 * 64 * 2);
    int* s32    = (int*)alloc((size_t)E * 4);
    int* d32    = (int*)alloc((size_t)E * 4);
    int* esrc   = (int*)alloc((size_t)Etot * 4);
    (void)ws_size; (void)n_in; (void)out_size;

    (void)hipMemsetAsync(cnt, 0, (size_t)N * 4, stream);

    k_detect<<<1, 64, 0, stream>>>(ei, flag);
    k_cvt<<<divup(E, 256), 256, 0, stream>>>(ei, E, flag, s32, d32, cnt);
    int nb = divup(N, 1024);
    k_scan1<<<nb, 1024, 0, stream>>>(cnt, N, rp, bsum);
    k_scan2<<<1, 64, 0, stream>>>(bsum, nb);
    k_scan3<<<divup(N + 1, 256), 256, 0, stream>>>(rp, bsum, N, Etot, cursor);
    k_scatter<<<2048, 256, 0, stream>>>(s32, d32, E, N, cursor, esrc);

    k_cvtW1<<<divup(512 * 128, 256), 256, 0, stream>>>(W1, W1t);
    k_cvtW2<<<divup(128 * 64, 256), 256, 0, stream>>>(W2, W2t);

    k_gemm1<<<divup(N, 128), 256, 0, stream>>>(x, W1t, b1, N, t1, n1);
    k_conv<<<divup(N, 4), 256, 0, stream>>>(t1, n1, rp, esrc, N, nullptr, t2, n2);
    k_conv<<<divup(N, 4), 256, 0, stream>>>(t2, n2, rp, esrc, N, beta2, t1, nullptr);
    k_gemm2<<<divup(N, 128), 256, 0, stream>>>(t1, W2t, b2, N, out);
}

// Round 8
// 435.515 us; speedup vs baseline: 1.0477x; 1.0417x over previous
//
#include <hip/hip_runtime.h>
#include <math.h>

// ---------------------------------------------------------------------------
// AGNN round 8: gemm1 rebuilt as "W-resident, A-streamed":
//  - W1t (128KB bf16) lives in LDS, staged in 2 K-phases of 256 (64KB each)
//    -> only 2 staging barriers per block (was 16 barrier-drains)
//  - x rows stream global->regs->bf16 directly in MFMA fragment layout;
//    register-double-buffered prefetch, ZERO barriers in the K-loop
//  - epilogue: fused normalize + LDS-bounce dense stores (kills the 3.7x
//    HBM write amplification seen in r7: WRITE 96.7MB vs 26MB ideal)
// conv = r4-verified 16 lanes/edge x 4; everything else identical to r7.
// ---------------------------------------------------------------------------

static inline int divup(int a, int b) { return (a + b - 1) / b; }

typedef __attribute__((ext_vector_type(8))) short short8;
typedef __attribute__((ext_vector_type(4))) float f32x4;
union U16 { uint4 u; short8 s; };

__device__ __forceinline__ unsigned bf16r(float f) {  // f32 -> bf16 bits, RNE
    unsigned u = __float_as_uint(f);
    return (u + 0x7FFFu + ((u >> 16) & 1u)) >> 16;
}
__device__ __forceinline__ unsigned pack2(float a, float b) {
    return bf16r(a) | (bf16r(b) << 16);
}
__device__ __forceinline__ float bflo(unsigned u) { return __uint_as_float(u << 16); }
__device__ __forceinline__ float bfhi(unsigned u) { return __uint_as_float(u & 0xFFFF0000u); }

// --- edge dtype detect / convert (+histogram fold) -------------------------
__global__ __launch_bounds__(64) void k_detect(const int* __restrict__ raw, int* flag) {
    int t = threadIdx.x;
    int v = raw[2 * t + 1];
    unsigned long long b = __ballot(v != 0);
    if (t == 0) *flag = (b == 0ULL) ? 1 : 0;  // 1 => int64 layout
}

__global__ __launch_bounds__(256) void k_cvt(const int* __restrict__ raw, int E,
                                             const int* __restrict__ flag,
                                             int* __restrict__ s32, int* __restrict__ d32,
                                             int* __restrict__ cnt) {
    int i = blockIdx.x * blockDim.x + threadIdx.x;
    if (i >= E) return;
    int s, d;
    if (*flag) {
        s = raw[2 * (size_t)i];
        d = raw[2 * ((size_t)E + i)];
    } else {
        s = raw[i];
        d = raw[(size_t)E + i];
    }
    s32[i] = s;
    d32[i] = d;
    atomicAdd(&cnt[d], 1);
}

// --- CSR scan (cnt + 1 self-loop per node) ---------------------------------
__global__ __launch_bounds__(1024) void k_scan1(const int* __restrict__ cnt, int N,
                                                int* __restrict__ rp, int* __restrict__ bsum) {
    __shared__ int sm[1024];
    int t = threadIdx.x;
    int i = blockIdx.x * 1024 + t;
    int v = (i < N) ? cnt[i] + 1 : 0;  // +1: self-loop
    sm[t] = v;
    __syncthreads();
#pragma unroll
    for (int off = 1; off < 1024; off <<= 1) {
        int u = (t >= off) ? sm[t - off] : 0;
        __syncthreads();
        sm[t] += u;
        __syncthreads();
    }
    if (i < N) rp[i] = sm[t] - v;  // exclusive
    if (t == 1023) bsum[blockIdx.x] = sm[t];
}

__global__ __launch_bounds__(64) void k_scan2(int* __restrict__ bsum, int nb) {
    if (threadIdx.x == 0) {
        int run = 0;
        for (int i = 0; i < nb; ++i) { int v = bsum[i]; bsum[i] = run; run += v; }
    }
}

__global__ __launch_bounds__(256) void k_scan3(int* __restrict__ rp, const int* __restrict__ bsum,
                                               int N, int Etot, int* __restrict__ cursor) {
    int i = blockIdx.x * blockDim.x + threadIdx.x;
    if (i < N) {
        int v = rp[i] + bsum[i >> 10];
        rp[i] = v;
        cursor[i] = v;
    } else if (i == N) {
        rp[N] = Etot;
    }
}

// --- XCD-partitioned scatter -----------------------------------------------
__global__ __launch_bounds__(256) void k_scatter(const int* __restrict__ s32,
                                                 const int* __restrict__ d32, int E, int N,
                                                 int* __restrict__ cursor,
                                                 int* __restrict__ esrc) {
    int b = blockIdx.x;
    int xcd = b & 7;
    int nstripe = gridDim.x >> 3;
    int stripe = b >> 3;
    int lo = (int)(((long long)xcd * N) >> 3);
    int hi = (int)(((long long)(xcd + 1) * N) >> 3);
    int Etot = E + N;
    for (int e = stripe * 256 + threadIdx.x; e < Etot; e += nstripe * 256) {
        int d = (e < E) ? d32[e] : (e - E);
        if (d < lo || d >= hi) continue;
        int s = (e < E) ? s32[e] : d;
        int pos = atomicAdd(&cursor[d], 1);
        esrc[pos] = s;
    }
}

// --- weight preconvert -----------------------------------------------------
__global__ __launch_bounds__(256) void k_cvtW1(const float* __restrict__ W1,
                                               unsigned short* __restrict__ W1t) {
    int i = blockIdx.x * 256 + threadIdx.x;
    if (i >= 512 * 128) return;
    int k = i >> 7, n = i & 127;
    W1t[n * 512 + k] = (unsigned short)bf16r(W1[i]);
}

__global__ __launch_bounds__(256) void k_cvtW2(const float* __restrict__ W2,
                                               unsigned short* __restrict__ W2t) {
    int i = blockIdx.x * 256 + threadIdx.x;
    if (i >= 128 * 64) return;
    int k = i >> 6, n = i & 63;
    W2t[n * 128 + k] = (unsigned short)bf16r(W2[i]);
}

// --- GEMM1: x_hat1/norm1 = normalize(relu(x @ W1 + b1)) --------------------
// W-resident / A-streamed. Block = 4 waves x 32 rows = 128 rows, 128 cols.
// LDS: W phase-tile [128 cols][256 k] bf16 = 64KB, XOR-swizzled per col.
#define XSW(c, off) ((off) ^ (((c) & 7) << 4))
__global__ __launch_bounds__(256) void k_gemm1(const float* __restrict__ x,
                                               const unsigned short* __restrict__ W1t,
                                               const float* __restrict__ b1, int N,
                                               unsigned short* __restrict__ xh1,
                                               float* __restrict__ n1) {
    __shared__ __align__(16) unsigned char lds[65536];
    const int tid = threadIdx.x;
    const int lane = tid & 63;
    const int lt = lane & 15, lg = lane >> 4;
    const int w = tid >> 6;
    const int row0 = blockIdx.x * 128;

    // per-lane A row pointers (clamped; rows >= N computed but never stored)
    const float* xb[2];
#pragma unroll
    for (int rf = 0; rf < 2; ++rf) {
        int r = row0 + w * 32 + rf * 16 + lt;
        if (r > N - 1) r = N - 1;
        xb[rf] = x + (size_t)r * 512 + lg * 8;
    }

    f32x4 acc[2][8];
#pragma unroll
    for (int i = 0; i < 2; ++i)
#pragma unroll
        for (int j = 0; j < 8; ++j) acc[i][j] = (f32x4){0.f, 0.f, 0.f, 0.f};

    for (int ph = 0; ph < 2; ++ph) {
        const int kb = ph * 256;
        // issue first A loads of this phase (latency overlaps W staging)
        float4 ac[2][2], an[2][2];
#pragma unroll
        for (int rf = 0; rf < 2; ++rf) {
            ac[rf][0] = ((const float4*)(xb[rf] + kb))[0];
            ac[rf][1] = ((const float4*)(xb[rf] + kb))[1];
        }
        // stage W[:, kb..kb+256) -> LDS  (2 threads/col, 256B each)
        __syncthreads();  // prior phase's B-frag reads done
        {
            int c = tid >> 1, h = tid & 1;
            const uint4* wp = (const uint4*)(W1t + c * 512 + kb + h * 128);
            unsigned char* base = lds + c * 512;
#pragma unroll
            for (int i = 0; i < 16; ++i)
                *(uint4*)(base + XSW(c, h * 256 + i * 16)) = wp[i];
        }
        __syncthreads();

        // barrier-free K-loop: 8 k-steps of 32, reg-dbuf A prefetch
#pragma unroll
        for (int ks = 0; ks < 8; ++ks) {
            if (ks < 7) {
#pragma unroll
                for (int rf = 0; rf < 2; ++rf) {
                    an[rf][0] = ((const float4*)(xb[rf] + kb + (ks + 1) * 32))[0];
                    an[rf][1] = ((const float4*)(xb[rf] + kb + (ks + 1) * 32))[1];
                }
            }
            U16 af[2];
#pragma unroll
            for (int rf = 0; rf < 2; ++rf) {
                af[rf].u.x = pack2(ac[rf][0].x, ac[rf][0].y);
                af[rf].u.y = pack2(ac[rf][0].z, ac[rf][0].w);
                af[rf].u.z = pack2(ac[rf][1].x, ac[rf][1].y);
                af[rf].u.w = pack2(ac[rf][1].z, ac[rf][1].w);
            }
#pragma unroll
            for (int cf = 0; cf < 8; ++cf) {
                int col = cf * 16 + lt;
                U16 bf;
                bf.u = *(const uint4*)(lds + col * 512 + XSW(col, ks * 64 + lg * 16));
#pragma unroll
                for (int rf = 0; rf < 2; ++rf)
                    acc[rf][cf] = __builtin_amdgcn_mfma_f32_16x16x32_bf16(
                        af[rf].s, bf.s, acc[rf][cf], 0, 0, 0);
            }
            if (ks < 7) {
#pragma unroll
                for (int rf = 0; rf < 2; ++rf) {
                    ac[rf][0] = an[rf][0];
                    ac[rf][1] = an[rf][1];
                }
            }
        }
    }

    // epilogue: bias+relu -> LDS rows -> norm -> pack -> LDS bounce -> dense
    float bias[8];
#pragma unroll
    for (int cf = 0; cf < 8; ++cf) bias[cf] = b1[cf * 16 + lt];
    float* sc = (float*)lds;              // 64 rows x 132 f32 = 33792B
    unsigned char* pk = lds + 36864;      // 16KB packed bf16 bounce
#pragma unroll 1
    for (int p = 0; p < 2; ++p) {
        __syncthreads();
        if ((w >> 1) == p) {
#pragma unroll
            for (int rf = 0; rf < 2; ++rf)
#pragma unroll
                for (int reg = 0; reg < 4; ++reg) {
                    int rl = (w & 1) * 32 + rf * 16 + lg * 4 + reg;
#pragma unroll
                    for (int cf = 0; cf < 8; ++cf)
                        sc[rl * 132 + cf * 16 + lt] =
                            fmaxf(acc[rf][cf][reg] + bias[cf], 0.f);
                }
        }
        __syncthreads();
        {
            int rl = tid >> 2, q = tid & 3;
            int gr = row0 + p * 64 + rl;
            const float* rowp = sc + rl * 132 + q * 32;
            float v[32];
#pragma unroll
            for (int i = 0; i < 8; ++i) {
                float4 f = ((const float4*)rowp)[i];
                v[4 * i] = f.x; v[4 * i + 1] = f.y; v[4 * i + 2] = f.z; v[4 * i + 3] = f.w;
            }
            float s2 = 0.f;
#pragma unroll
            for (int i = 0; i < 32; ++i) s2 += v[i] * v[i];
            s2 += __shfl_xor(s2, 1, 64);
            s2 += __shfl_xor(s2, 2, 64);
            float nrm = sqrtf(s2);
            float rn = 1.0f / fmaxf(nrm, 1e-12f);
            uint4 o[4];
            unsigned* op = (unsigned*)o;
#pragma unroll
            for (int i = 0; i < 16; ++i)
                op[i] = pack2(v[2 * i] * rn, v[2 * i + 1] * rn);
            uint4* pd = (uint4*)(pk + rl * 256 + q * 64);
            pd[0] = o[0]; pd[1] = o[1]; pd[2] = o[2]; pd[3] = o[3];
            if (q == 0 && gr < N) n1[gr] = nrm;
        }
        __syncthreads();
#pragma unroll
        for (int j = 0; j < 4; ++j) {
            int boff = j * 4096 + tid * 16;
            int r = boff >> 8;
            int gr = row0 + p * 64 + r;
            if (gr < N)
                *(uint4*)((unsigned char*)xh1 + (size_t)gr * 256 + (boff & 255)) =
                    *(const uint4*)(pk + boff);
        }
    }
}

// --- AGNN conv (r4 structure): wave/node, 16 lanes/edge, 4 edges/round -----
__global__ __launch_bounds__(256) void k_conv(const unsigned short* __restrict__ xh,
                                              const float* __restrict__ nrmt,
                                              const int* __restrict__ rp,
                                              const int* __restrict__ esrc, int N,
                                              const float* __restrict__ betap,
                                              unsigned short* __restrict__ outh,
                                              float* __restrict__ outn) {
    int node = (blockIdx.x * blockDim.x + threadIdx.x) >> 6;
    if (node >= N) return;
    int lane = threadIdx.x & 63;
    int t = lane & 15, g = lane >> 4;
    float beta = betap ? *betap : 1.0f;

    uint4 hdu = *(const uint4*)&xh[(size_t)node * 128 + 8 * t];
    float hd[8];
    hd[0] = bflo(hdu.x); hd[1] = bfhi(hdu.x);
    hd[2] = bflo(hdu.y); hd[3] = bfhi(hdu.y);
    hd[4] = bflo(hdu.z); hd[5] = bfhi(hdu.z);
    hd[6] = bflo(hdu.w); hd[7] = bfhi(hdu.w);

    int e0 = rp[node], e1 = rp[node + 1];
    float acc[8] = {0.f, 0.f, 0.f, 0.f, 0.f, 0.f, 0.f, 0.f};
    float ssum = 0.f;

    for (int eb = e0; eb < e1; eb += 4) {
        int e = eb + g;
        int ee = (e < e1) ? e : e0;
        int s = esrc[ee];
        float ns = nrmt[s];
        uint4 hu = *(const uint4*)&xh[(size_t)s * 128 + 8 * t];
        float v[8];
        v[0] = bflo(hu.x); v[1] = bfhi(hu.x);
        v[2] = bflo(hu.y); v[3] = bfhi(hu.y);
        v[4] = bflo(hu.z); v[5] = bfhi(hu.z);
        v[6] = bflo(hu.w); v[7] = bfhi(hu.w);
        float p = 0.f;
#pragma unroll
        for (int j = 0; j < 8; ++j) p += v[j] * hd[j];
        p += __shfl_xor(p, 1, 64);
        p += __shfl_xor(p, 2, 64);
        p += __shfl_xor(p, 4, 64);
        p += __shfl_xor(p, 8, 64);
        float w = (e < e1) ? __expf(p * beta) : 0.f;
        float wn = w * ns;
        ssum += w;
#pragma unroll
        for (int j = 0; j < 8; ++j) acc[j] += wn * v[j];
    }
#pragma unroll
    for (int j = 0; j < 8; ++j) {
        acc[j] += __shfl_xor(acc[j], 16, 64);
        acc[j] += __shfl_xor(acc[j], 32, 64);
    }
    ssum += __shfl_xor(ssum, 16, 64);
    ssum += __shfl_xor(ssum, 32, 64);
    float r = 1.0f / ssum;

    if (outn == nullptr) {
        if (g == 0) {
            uint4 q;
            q.x = pack2(acc[0] * r, acc[1] * r);
            q.y = pack2(acc[2] * r, acc[3] * r);
            q.z = pack2(acc[4] * r, acc[5] * r);
            q.w = pack2(acc[6] * r, acc[7] * r);
            *(uint4*)&outh[(size_t)node * 128 + 8 * t] = q;
        }
    } else {
        float o[8];
        float s2 = 0.f;
#pragma unroll
        for (int j = 0; j < 8; ++j) { o[j] = acc[j] * r; s2 += o[j] * o[j]; }
        s2 += __shfl_xor(s2, 1, 64);
        s2 += __shfl_xor(s2, 2, 64);
        s2 += __shfl_xor(s2, 4, 64);
        s2 += __shfl_xor(s2, 8, 64);
        float nn = sqrtf(s2);
        float rn = 1.0f / fmaxf(nn, 1e-12f);
        if (g == 0) {
            uint4 q;
            q.x = pack2(o[0] * rn, o[1] * rn);
            q.y = pack2(o[2] * rn, o[3] * rn);
            q.z = pack2(o[4] * rn, o[5] * rn);
            q.w = pack2(o[6] * rn, o[7] * rn);
            *(uint4*)&outh[(size_t)node * 128 + 8 * t] = q;
            if (t == 0) outn[node] = nn;
        }
    }
}

// --- GEMM2 (MFMA) + fused log_softmax --------------------------------------
#define G2_ASTRIDE 272
__global__ __launch_bounds__(256) void k_gemm2(const unsigned short* __restrict__ h,
                                               const unsigned short* __restrict__ W2t,
                                               const float* __restrict__ b2, int N,
                                               float* __restrict__ out) {
    __shared__ __align__(16) unsigned char As[128 * G2_ASTRIDE];
    __shared__ __align__(16) unsigned char Bs[64 * G2_ASTRIDE];
    const int tid = threadIdx.x;
    const int lane = tid & 63;
    const int lt = lane & 15, lg = lane >> 4;
    const int wid = tid >> 6;
    const int row0 = blockIdx.x * 128;

    {
        int arow = tid >> 1, ahalf = tid & 1;
        const uint4* src = (const uint4*)(h + (size_t)(row0 + arow) * 128 + ahalf * 64);
        unsigned char* ab = As + arow * G2_ASTRIDE + ahalf * 128;
#pragma unroll
        for (int i = 0; i < 8; ++i) ((uint4*)ab)[i] = src[i];
        int brow = tid >> 2, bq = tid & 3;
        const uint4* bs = (const uint4*)(W2t + (size_t)brow * 128 + bq * 32);
        unsigned char* bb = Bs + brow * G2_ASTRIDE + bq * 64;
#pragma unroll
        for (int i = 0; i < 4; ++i) ((uint4*)bb)[i] = bs[i];
    }
    __syncthreads();

    f32x4 acc[2][4];
#pragma unroll
    for (int i = 0; i < 2; ++i)
#pragma unroll
        for (int j = 0; j < 4; ++j) acc[i][j] = (f32x4){0.f, 0.f, 0.f, 0.f};

#pragma unroll
    for (int sub = 0; sub < 4; ++sub) {
        U16 af[2], bf[4];
#pragma unroll
        for (int mi = 0; mi < 2; ++mi)
            af[mi].u = *(const uint4*)(As + (wid * 32 + mi * 16 + lt) * G2_ASTRIDE + sub * 64 + lg * 16);
#pragma unroll
        for (int ni = 0; ni < 4; ++ni)
            bf[ni].u = *(const uint4*)(Bs + (ni * 16 + lt) * G2_ASTRIDE + sub * 64 + lg * 16);
#pragma unroll
        for (int mi = 0; mi < 2; ++mi)
#pragma unroll
            for (int ni = 0; ni < 4; ++ni)
                acc[mi][ni] = __builtin_amdgcn_mfma_f32_16x16x32_bf16(
                    af[mi].s, bf[ni].s, acc[mi][ni], 0, 0, 0);
    }

    float bias[4];
#pragma unroll
    for (int ni = 0; ni < 4; ++ni) bias[ni] = b2[ni * 16 + lt];

#pragma unroll
    for (int mi = 0; mi < 2; ++mi) {
#pragma unroll
        for (int reg = 0; reg < 4; ++reg) {
            int row = row0 + wid * 32 + mi * 16 + lg * 4 + reg;
            if (row < N) {
                float v[4];
#pragma unroll
                for (int ni = 0; ni < 4; ++ni) v[ni] = acc[mi][ni][reg] + bias[ni];
                float m = fmaxf(fmaxf(v[0], v[1]), fmaxf(v[2], v[3]));
                m = fmaxf(m, __shfl_xor(m, 1, 64));
                m = fmaxf(m, __shfl_xor(m, 2, 64));
                m = fmaxf(m, __shfl_xor(m, 4, 64));
                m = fmaxf(m, __shfl_xor(m, 8, 64));
                float s = __expf(v[0] - m) + __expf(v[1] - m) +
                          __expf(v[2] - m) + __expf(v[3] - m);
                s += __shfl_xor(s, 1, 64);
                s += __shfl_xor(s, 2, 64);
                s += __shfl_xor(s, 4, 64);
                s += __shfl_xor(s, 8, 64);
                float lg2 = logf(s);
#pragma unroll
                for (int ni = 0; ni < 4; ++ni)
                    out[(size_t)row * 64 + ni * 16 + lt] = v[ni] - m - lg2;
            }
        }
    }
}

// ---------------------------------------------------------------------------
extern "C" void kernel_launch(void* const* d_in, const int* in_sizes, int n_in,
                              void* d_out, int out_size, void* d_ws, size_t ws_size,
                              hipStream_t stream) {
    const float* x     = (const float*)d_in[0];
    const int*   ei    = (const int*)d_in[1];
    const float* W1    = (const float*)d_in[2];
    const float* b1    = (const float*)d_in[3];
    const float* beta2 = (const float*)d_in[4];
    const float* W2    = (const float*)d_in[5];
    const float* b2    = (const float*)d_in[6];
    float* out = (float*)d_out;

    const int N = in_sizes[0] / 512;
    const int E = in_sizes[1] / 2;
    const int Etot = E + N;

    char* ws = (char*)d_ws;
    size_t off = 0;
    auto alloc = [&](size_t bytes) -> void* {
        void* p = ws + off;
        off = (off + bytes + 511) & ~(size_t)511;
        return p;
    };
    unsigned short* t1 = (unsigned short*)alloc((size_t)N * 128 * 2);  // x_hat1 / h3
    unsigned short* t2 = (unsigned short*)alloc((size_t)N * 128 * 2);  // x_hat2
    float* n1   = (float*)alloc((size_t)N * 4);
    float* n2   = (float*)alloc((size_t)N * 4);
    int* cnt    = (int*)alloc((size_t)N * 4);
    int* rp     = (int*)alloc((size_t)(N + 1) * 4);
    int* cursor = (int*)alloc((size_t)N * 4);
    int* bsum   = (int*)alloc(4096);
    int* flag   = (int*)alloc(512);
    unsigned short* W1t = (unsigned short*)alloc(512 * 128 * 2);
    unsigned short* W2t = (unsigned short*)alloc(128 * 64 * 2);
    int* s32    = (int*)alloc((size_t)E * 4);
    int* d32    = (int*)alloc((size_t)E * 4);
    int* esrc   = (int*)alloc((size_t)Etot * 4);
    (void)ws_size; (void)n_in; (void)out_size;

    (void)hipMemsetAsync(cnt, 0, (size_t)N * 4, stream);

    k_detect<<<1, 64, 0, stream>>>(ei, flag);
    k_cvt<<<divup(E, 256), 256, 0, stream>>>(ei, E, flag, s32, d32, cnt);
    int nb = divup(N, 1024);
    k_scan1<<<nb, 1024, 0, stream>>>(cnt, N, rp, bsum);
    k_scan2<<<1, 64, 0, stream>>>(bsum, nb);
    k_scan3<<<divup(N + 1, 256), 256, 0, stream>>>(rp, bsum, N, Etot, cursor);
    k_scatter<<<2048, 256, 0, stream>>>(s32, d32, E, N, cursor, esrc);

    k_cvtW1<<<divup(512 * 128, 256), 256, 0, stream>>>(W1, W1t);
    k_cvtW2<<<divup(128 * 64, 256), 256, 0, stream>>>(W2, W2t);

    k_gemm1<<<divup(N, 128), 256, 0, stream>>>(x, W1t, b1, N, t1, n1);
    k_conv<<<divup(N, 4), 256, 0, stream>>>(t1, n1, rp, esrc, N, nullptr, t2, n2);
    k_conv<<<divup(N, 4), 256, 0, stream>>>(t2, n2, rp, esrc, N, beta2, t1, nullptr);
    k_gemm2<<<divup(N, 128), 256, 0, stream>>>(t1, W2t, b2, N, out);
}

// Round 9
// 416.260 us; speedup vs baseline: 1.0962x; 1.0463x over previous
//
#include <hip/hip_runtime.h>
#include <math.h>

// ---------------------------------------------------------------------------
// AGNN round 9: conv software-pipelined 2-deep (keep r4's verified 16x4
// geometry): idx for round k+1 prefetched in round k-1, row gather for k+1
// issued before round k's compute -> gather latency hides under dot/shfl/exp.
// All rotation branches wave-uniform. Math bit-identical to r4/r8.
// gemm1 = r8 W-resident/A-streamed (verified); rest identical to r8.
// ---------------------------------------------------------------------------

static inline int divup(int a, int b) { return (a + b - 1) / b; }

typedef __attribute__((ext_vector_type(8))) short short8;
typedef __attribute__((ext_vector_type(4))) float f32x4;
union U16 { uint4 u; short8 s; };

__device__ __forceinline__ unsigned bf16r(float f) {  // f32 -> bf16 bits, RNE
    unsigned u = __float_as_uint(f);
    return (u + 0x7FFFu + ((u >> 16) & 1u)) >> 16;
}
__device__ __forceinline__ unsigned pack2(float a, float b) {
    return bf16r(a) | (bf16r(b) << 16);
}
__device__ __forceinline__ float bflo(unsigned u) { return __uint_as_float(u << 16); }
__device__ __forceinline__ float bfhi(unsigned u) { return __uint_as_float(u & 0xFFFF0000u); }

// --- edge dtype detect / convert (+histogram fold) -------------------------
__global__ __launch_bounds__(64) void k_detect(const int* __restrict__ raw, int* flag) {
    int t = threadIdx.x;
    int v = raw[2 * t + 1];
    unsigned long long b = __ballot(v != 0);
    if (t == 0) *flag = (b == 0ULL) ? 1 : 0;  // 1 => int64 layout
}

__global__ __launch_bounds__(256) void k_cvt(const int* __restrict__ raw, int E,
                                             const int* __restrict__ flag,
                                             int* __restrict__ s32, int* __restrict__ d32,
                                             int* __restrict__ cnt) {
    int i = blockIdx.x * blockDim.x + threadIdx.x;
    if (i >= E) return;
    int s, d;
    if (*flag) {
        s = raw[2 * (size_t)i];
        d = raw[2 * ((size_t)E + i)];
    } else {
        s = raw[i];
        d = raw[(size_t)E + i];
    }
    s32[i] = s;
    d32[i] = d;
    atomicAdd(&cnt[d], 1);
}

// --- CSR scan (cnt + 1 self-loop per node) ---------------------------------
__global__ __launch_bounds__(1024) void k_scan1(const int* __restrict__ cnt, int N,
                                                int* __restrict__ rp, int* __restrict__ bsum) {
    __shared__ int sm[1024];
    int t = threadIdx.x;
    int i = blockIdx.x * 1024 + t;
    int v = (i < N) ? cnt[i] + 1 : 0;  // +1: self-loop
    sm[t] = v;
    __syncthreads();
#pragma unroll
    for (int off = 1; off < 1024; off <<= 1) {
        int u = (t >= off) ? sm[t - off] : 0;
        __syncthreads();
        sm[t] += u;
        __syncthreads();
    }
    if (i < N) rp[i] = sm[t] - v;  // exclusive
    if (t == 1023) bsum[blockIdx.x] = sm[t];
}

__global__ __launch_bounds__(64) void k_scan2(int* __restrict__ bsum, int nb) {
    if (threadIdx.x == 0) {
        int run = 0;
        for (int i = 0; i < nb; ++i) { int v = bsum[i]; bsum[i] = run; run += v; }
    }
}

__global__ __launch_bounds__(256) void k_scan3(int* __restrict__ rp, const int* __restrict__ bsum,
                                               int N, int Etot, int* __restrict__ cursor) {
    int i = blockIdx.x * blockDim.x + threadIdx.x;
    if (i < N) {
        int v = rp[i] + bsum[i >> 10];
        rp[i] = v;
        cursor[i] = v;
    } else if (i == N) {
        rp[N] = Etot;
    }
}

// --- XCD-partitioned scatter -----------------------------------------------
__global__ __launch_bounds__(256) void k_scatter(const int* __restrict__ s32,
                                                 const int* __restrict__ d32, int E, int N,
                                                 int* __restrict__ cursor,
                                                 int* __restrict__ esrc) {
    int b = blockIdx.x;
    int xcd = b & 7;
    int nstripe = gridDim.x >> 3;
    int stripe = b >> 3;
    int lo = (int)(((long long)xcd * N) >> 3);
    int hi = (int)(((long long)(xcd + 1) * N) >> 3);
    int Etot = E + N;
    for (int e = stripe * 256 + threadIdx.x; e < Etot; e += nstripe * 256) {
        int d = (e < E) ? d32[e] : (e - E);
        if (d < lo || d >= hi) continue;
        int s = (e < E) ? s32[e] : d;
        int pos = atomicAdd(&cursor[d], 1);
        esrc[pos] = s;
    }
}

// --- weight preconvert -----------------------------------------------------
__global__ __launch_bounds__(256) void k_cvtW1(const float* __restrict__ W1,
                                               unsigned short* __restrict__ W1t) {
    int i = blockIdx.x * 256 + threadIdx.x;
    if (i >= 512 * 128) return;
    int k = i >> 7, n = i & 127;
    W1t[n * 512 + k] = (unsigned short)bf16r(W1[i]);
}

__global__ __launch_bounds__(256) void k_cvtW2(const float* __restrict__ W2,
                                               unsigned short* __restrict__ W2t) {
    int i = blockIdx.x * 256 + threadIdx.x;
    if (i >= 128 * 64) return;
    int k = i >> 6, n = i & 63;
    W2t[n * 128 + k] = (unsigned short)bf16r(W2[i]);
}

// --- GEMM1: x_hat1/norm1 = normalize(relu(x @ W1 + b1)) --------------------
// W-resident / A-streamed (r8, verified). Zero barriers in K-loop.
#define XSW(c, off) ((off) ^ (((c) & 7) << 4))
__global__ __launch_bounds__(256) void k_gemm1(const float* __restrict__ x,
                                               const unsigned short* __restrict__ W1t,
                                               const float* __restrict__ b1, int N,
                                               unsigned short* __restrict__ xh1,
                                               float* __restrict__ n1) {
    __shared__ __align__(16) unsigned char lds[65536];
    const int tid = threadIdx.x;
    const int lane = tid & 63;
    const int lt = lane & 15, lg = lane >> 4;
    const int w = tid >> 6;
    const int row0 = blockIdx.x * 128;

    const float* xb[2];
#pragma unroll
    for (int rf = 0; rf < 2; ++rf) {
        int r = row0 + w * 32 + rf * 16 + lt;
        if (r > N - 1) r = N - 1;
        xb[rf] = x + (size_t)r * 512 + lg * 8;
    }

    f32x4 acc[2][8];
#pragma unroll
    for (int i = 0; i < 2; ++i)
#pragma unroll
        for (int j = 0; j < 8; ++j) acc[i][j] = (f32x4){0.f, 0.f, 0.f, 0.f};

    for (int ph = 0; ph < 2; ++ph) {
        const int kb = ph * 256;
        float4 ac[2][2], an[2][2];
#pragma unroll
        for (int rf = 0; rf < 2; ++rf) {
            ac[rf][0] = ((const float4*)(xb[rf] + kb))[0];
            ac[rf][1] = ((const float4*)(xb[rf] + kb))[1];
        }
        __syncthreads();
        {
            int c = tid >> 1, h = tid & 1;
            const uint4* wp = (const uint4*)(W1t + c * 512 + kb + h * 128);
            unsigned char* base = lds + c * 512;
#pragma unroll
            for (int i = 0; i < 16; ++i)
                *(uint4*)(base + XSW(c, h * 256 + i * 16)) = wp[i];
        }
        __syncthreads();

#pragma unroll
        for (int ks = 0; ks < 8; ++ks) {
            if (ks < 7) {
#pragma unroll
                for (int rf = 0; rf < 2; ++rf) {
                    an[rf][0] = ((const float4*)(xb[rf] + kb + (ks + 1) * 32))[0];
                    an[rf][1] = ((const float4*)(xb[rf] + kb + (ks + 1) * 32))[1];
                }
            }
            U16 af[2];
#pragma unroll
            for (int rf = 0; rf < 2; ++rf) {
                af[rf].u.x = pack2(ac[rf][0].x, ac[rf][0].y);
                af[rf].u.y = pack2(ac[rf][0].z, ac[rf][0].w);
                af[rf].u.z = pack2(ac[rf][1].x, ac[rf][1].y);
                af[rf].u.w = pack2(ac[rf][1].z, ac[rf][1].w);
            }
#pragma unroll
            for (int cf = 0; cf < 8; ++cf) {
                int col = cf * 16 + lt;
                U16 bf;
                bf.u = *(const uint4*)(lds + col * 512 + XSW(col, ks * 64 + lg * 16));
#pragma unroll
                for (int rf = 0; rf < 2; ++rf)
                    acc[rf][cf] = __builtin_amdgcn_mfma_f32_16x16x32_bf16(
                        af[rf].s, bf.s, acc[rf][cf], 0, 0, 0);
            }
            if (ks < 7) {
#pragma unroll
                for (int rf = 0; rf < 2; ++rf) {
                    ac[rf][0] = an[rf][0];
                    ac[rf][1] = an[rf][1];
                }
            }
        }
    }

    float bias[8];
#pragma unroll
    for (int cf = 0; cf < 8; ++cf) bias[cf] = b1[cf * 16 + lt];
    float* sc = (float*)lds;              // 64 rows x 132 f32 = 33792B
    unsigned char* pk = lds + 36864;      // 16KB packed bf16 bounce
#pragma unroll 1
    for (int p = 0; p < 2; ++p) {
        __syncthreads();
        if ((w >> 1) == p) {
#pragma unroll
            for (int rf = 0; rf < 2; ++rf)
#pragma unroll
                for (int reg = 0; reg < 4; ++reg) {
                    int rl = (w & 1) * 32 + rf * 16 + lg * 4 + reg;
#pragma unroll
                    for (int cf = 0; cf < 8; ++cf)
                        sc[rl * 132 + cf * 16 + lt] =
                            fmaxf(acc[rf][cf][reg] + bias[cf], 0.f);
                }
        }
        __syncthreads();
        {
            int rl = tid >> 2, q = tid & 3;
            int gr = row0 + p * 64 + rl;
            const float* rowp = sc + rl * 132 + q * 32;
            float v[32];
#pragma unroll
            for (int i = 0; i < 8; ++i) {
                float4 f = ((const float4*)rowp)[i];
                v[4 * i] = f.x; v[4 * i + 1] = f.y; v[4 * i + 2] = f.z; v[4 * i + 3] = f.w;
            }
            float s2 = 0.f;
#pragma unroll
            for (int i = 0; i < 32; ++i) s2 += v[i] * v[i];
            s2 += __shfl_xor(s2, 1, 64);
            s2 += __shfl_xor(s2, 2, 64);
            float nrm = sqrtf(s2);
            float rn = 1.0f / fmaxf(nrm, 1e-12f);
            uint4 o[4];
            unsigned* op = (unsigned*)o;
#pragma unroll
            for (int i = 0; i < 16; ++i)
                op[i] = pack2(v[2 * i] * rn, v[2 * i + 1] * rn);
            uint4* pd = (uint4*)(pk + rl * 256 + q * 64);
            pd[0] = o[0]; pd[1] = o[1]; pd[2] = o[2]; pd[3] = o[3];
            if (q == 0 && gr < N) n1[gr] = nrm;
        }
        __syncthreads();
#pragma unroll
        for (int j = 0; j < 4; ++j) {
            int boff = j * 4096 + tid * 16;
            int r = boff >> 8;
            int gr = row0 + p * 64 + r;
            if (gr < N)
                *(uint4*)((unsigned char*)xh1 + (size_t)gr * 256 + (boff & 255)) =
                    *(const uint4*)(pk + boff);
        }
    }
}

// --- AGNN conv: r4 16x4 geometry, software-pipelined 2-deep ----------------
__global__ __launch_bounds__(256) void k_conv(const unsigned short* __restrict__ xh,
                                              const float* __restrict__ nrmt,
                                              const int* __restrict__ rp,
                                              const int* __restrict__ esrc, int N,
                                              const float* __restrict__ betap,
                                              unsigned short* __restrict__ outh,
                                              float* __restrict__ outn) {
    int node = (blockIdx.x * blockDim.x + threadIdx.x) >> 6;
    if (node >= N) return;
    int lane = threadIdx.x & 63;
    int t = lane & 15, g = lane >> 4;
    float beta = betap ? *betap : 1.0f;

    uint4 hdu = *(const uint4*)&xh[(size_t)node * 128 + 8 * t];
    float hd[8];
    hd[0] = bflo(hdu.x); hd[1] = bfhi(hdu.x);
    hd[2] = bflo(hdu.y); hd[3] = bfhi(hdu.y);
    hd[4] = bflo(hdu.z); hd[5] = bfhi(hdu.z);
    hd[6] = bflo(hdu.w); hd[7] = bfhi(hdu.w);

    int e0 = rp[node], e1 = rp[node + 1];
    float acc[8] = {0.f, 0.f, 0.f, 0.f, 0.f, 0.f, 0.f, 0.f};
    float ssum = 0.f;

    // pipeline prologue: round-0 row in flight, round-1 index in flight
    int eA = e0 + g;
    int sA = esrc[(eA < e1) ? eA : e0];
    uint4 rowA = *(const uint4*)&xh[(size_t)sA * 128 + 8 * t];
    float nsA = nrmt[sA];
    int eB = e0 + 4 + g;
    int sB = esrc[(eB < e1) ? eB : e0];

    for (int eb = e0; eb < e1; eb += 4) {
        // issue next round's gathers (index already resident)
        uint4 rowB;
        float nsB = 0.f;
        const bool hasNext = (eb + 4) < e1;  // wave-uniform
        if (hasNext) {
            rowB = *(const uint4*)&xh[(size_t)sB * 128 + 8 * t];
            nsB = nrmt[sB];
        }
        // prefetch index for round k+2
        int eC = eb + 8 + g;
        int sC = esrc[(eC < e1) ? eC : e0];

        // compute current round (identical math to r4)
        float v[8];
        v[0] = bflo(rowA.x); v[1] = bfhi(rowA.x);
        v[2] = bflo(rowA.y); v[3] = bfhi(rowA.y);
        v[4] = bflo(rowA.z); v[5] = bfhi(rowA.z);
        v[6] = bflo(rowA.w); v[7] = bfhi(rowA.w);
        float p = 0.f;
#pragma unroll
        for (int j = 0; j < 8; ++j) p += v[j] * hd[j];
        p += __shfl_xor(p, 1, 64);
        p += __shfl_xor(p, 2, 64);
        p += __shfl_xor(p, 4, 64);
        p += __shfl_xor(p, 8, 64);
        int e = eb + g;
        float w = (e < e1) ? __expf(p * beta) : 0.f;
        float wn = w * nsA;
        ssum += w;
#pragma unroll
        for (int j = 0; j < 8; ++j) acc[j] += wn * v[j];

        // rotate pipeline
        if (hasNext) {
            rowA = rowB;
            nsA = nsB;
        }
        sB = sC;
    }
#pragma unroll
    for (int j = 0; j < 8; ++j) {
        acc[j] += __shfl_xor(acc[j], 16, 64);
        acc[j] += __shfl_xor(acc[j], 32, 64);
    }
    ssum += __shfl_xor(ssum, 16, 64);
    ssum += __shfl_xor(ssum, 32, 64);
    float r = 1.0f / ssum;

    if (outn == nullptr) {
        if (g == 0) {
            uint4 q;
            q.x = pack2(acc[0] * r, acc[1] * r);
            q.y = pack2(acc[2] * r, acc[3] * r);
            q.z = pack2(acc[4] * r, acc[5] * r);
            q.w = pack2(acc[6] * r, acc[7] * r);
            *(uint4*)&outh[(size_t)node * 128 + 8 * t] = q;
        }
    } else {
        float o[8];
        float s2 = 0.f;
#pragma unroll
        for (int j = 0; j < 8; ++j) { o[j] = acc[j] * r; s2 += o[j] * o[j]; }
        s2 += __shfl_xor(s2, 1, 64);
        s2 += __shfl_xor(s2, 2, 64);
        s2 += __shfl_xor(s2, 4, 64);
        s2 += __shfl_xor(s2, 8, 64);
        float nn = sqrtf(s2);
        float rn = 1.0f / fmaxf(nn, 1e-12f);
        if (g == 0) {
            uint4 q;
            q.x = pack2(o[0] * rn, o[1] * rn);
            q.y = pack2(o[2] * rn, o[3] * rn);
            q.z = pack2(o[4] * rn, o[5] * rn);
            q.w = pack2(o[6] * rn, o[7] * rn);
            *(uint4*)&outh[(size_t)node * 128 + 8 * t] = q;
            if (t == 0) outn[node] = nn;
        }
    }
}

// --- GEMM2 (MFMA) + fused log_softmax --------------------------------------
#define G2_ASTRIDE 272
__global__ __launch_bounds__(256) void k_gemm2(const unsigned short* __restrict__ h,
                                               const unsigned short* __restrict__ W2t,
                                               const float* __restrict__ b2, int N,
                                               float* __restrict__ out) {
    __shared__ __align__(16) unsigned char As[128 * G2_ASTRIDE];
    __shared__ __align__(16) unsigned char Bs[64 * G2_ASTRIDE];
    const int tid = threadIdx.x;
    const int lane = tid & 63;
    const int lt = lane & 15, lg = lane >> 4;
    const int wid = tid >> 6;
    const int row0 = blockIdx.x * 128;

    {
        int arow = tid >> 1, ahalf = tid & 1;
        const uint4* src = (const uint4*)(h + (size_t)(row0 + arow) * 128 + ahalf * 64);
        unsigned char* ab = As + arow * G2_ASTRIDE + ahalf * 128;
#pragma unroll
        for (int i = 0; i < 8; ++i) ((uint4*)ab)[i] = src[i];
        int brow = tid >> 2, bq = tid & 3;
        const uint4* bs = (const uint4*)(W2t + (size_t)brow * 128 + bq * 32);
        unsigned char* bb = Bs + brow * G2_ASTRIDE + bq * 64;
#pragma unroll
        for (int i = 0; i < 4; ++i) ((uint4*)bb)[i] = bs[i];
    }
    __syncthreads();

    f32x4 acc[2][4];
#pragma unroll
    for (int i = 0; i < 2; ++i)
#pragma unroll
        for (int j = 0; j < 4; ++j) acc[i][j] = (f32x4){0.f, 0.f, 0.f, 0.f};

#pragma unroll
    for (int sub = 0; sub < 4; ++sub) {
        U16 af[2], bf[4];
#pragma unroll
        for (int mi = 0; mi < 2; ++mi)
            af[mi].u = *(const uint4*)(As + (wid * 32 + mi * 16 + lt) * G2_ASTRIDE + sub * 64 + lg * 16);
#pragma unroll
        for (int ni = 0; ni < 4; ++ni)
            bf[ni].u = *(const uint4*)(Bs + (ni * 16 + lt) * G2_ASTRIDE + sub * 64 + lg * 16);
#pragma unroll
        for (int mi = 0; mi < 2; ++mi)
#pragma unroll
            for (int ni = 0; ni < 4; ++ni)
                acc[mi][ni] = __builtin_amdgcn_mfma_f32_16x16x32_bf16(
                    af[mi].s, bf[ni].s, acc[mi][ni], 0, 0, 0);
    }

    float bias[4];
#pragma unroll
    for (int ni = 0; ni < 4; ++ni) bias[ni] = b2[ni * 16 + lt];

#pragma unroll
    for (int mi = 0; mi < 2; ++mi) {
#pragma unroll
        for (int reg = 0; reg < 4; ++reg) {
            int row = row0 + wid * 32 + mi * 16 + lg * 4 + reg;
            if (row < N) {
                float v[4];
#pragma unroll
                for (int ni = 0; ni < 4; ++ni) v[ni] = acc[mi][ni][reg] + bias[ni];
                float m = fmaxf(fmaxf(v[0], v[1]), fmaxf(v[2], v[3]));
                m = fmaxf(m, __shfl_xor(m, 1, 64));
                m = fmaxf(m, __shfl_xor(m, 2, 64));
                m = fmaxf(m, __shfl_xor(m, 4, 64));
                m = fmaxf(m, __shfl_xor(m, 8, 64));
                float s = __expf(v[0] - m) + __expf(v[1] - m) +
                          __expf(v[2] - m) + __expf(v[3] - m);
                s += __shfl_xor(s, 1, 64);
                s += __shfl_xor(s, 2, 64);
                s += __shfl_xor(s, 4, 64);
                s += __shfl_xor(s, 8, 64);
                float lg2 = logf(s);
#pragma unroll
                for (int ni = 0; ni < 4; ++ni)
                    out[(size_t)row * 64 + ni * 16 + lt] = v[ni] - m - lg2;
            }
        }
    }
}

// ---------------------------------------------------------------------------
extern "C" void kernel_launch(void* const* d_in, const int* in_sizes, int n_in,
                              void* d_out, int out_size, void* d_ws, size_t ws_size,
                              hipStream_t stream) {
    const float* x     = (const float*)d_in[0];
    const int*   ei    = (const int*)d_in[1];
    const float* W1    = (const float*)d_in[2];
    const float* b1    = (const float*)d_in[3];
    const float* beta2 = (const float*)d_in[4];
    const float* W2    = (const float*)d_in[5];
    const float* b2    = (const float*)d_in[6];
    float* out = (float*)d_out;

    const int N = in_sizes[0] / 512;
    const int E = in_sizes[1] / 2;
    const int Etot = E + N;

    char* ws = (char*)d_ws;
    size_t off = 0;
    auto alloc = [&](size_t bytes) -> void* {
        void* p = ws + off;
        off = (off + bytes + 511) & ~(size_t)511;
        return p;
    };
    unsigned short* t1 = (unsigned short*)alloc((size_t)N * 128 * 2);  // x_hat1 / h3
    unsigned short* t2 = (unsigned short*)alloc((size_t)N * 128 * 2);  // x_hat2
    float* n1   = (float*)alloc((size_t)N * 4);
    float* n2   = (float*)alloc((size_t)N * 4);
    int* cnt    = (int*)alloc((size_t)N * 4);
    int* rp     = (int*)alloc((size_t)(N + 1) * 4);
    int* cursor = (int*)alloc((size_t)N * 4);
    int* bsum   = (int*)alloc(4096);
    int* flag   = (int*)alloc(512);
    unsigned short* W1t = (unsigned short*)alloc(512 * 128 * 2);
    unsigned short* W2t = (unsigned short*)alloc(128 * 64 * 2);
    int* s32    = (int*)alloc((size_t)E * 4);
    int* d32    = (int*)alloc((size_t)E * 4);
    int* esrc   = (int*)alloc((size_t)Etot * 4);
    (void)ws_size; (void)n_in; (void)out_size;

    (void)hipMemsetAsync(cnt, 0, (size_t)N * 4, stream);

    k_detect<<<1, 64, 0, stream>>>(ei, flag);
    k_cvt<<<divup(E, 256), 256, 0, stream>>>(ei, E, flag, s32, d32, cnt);
    int nb = divup(N, 1024);
    k_scan1<<<nb, 1024, 0, stream>>>(cnt, N, rp, bsum);
    k_scan2<<<1, 64, 0, stream>>>(bsum, nb);
    k_scan3<<<divup(N + 1, 256), 256, 0, stream>>>(rp, bsum, N, Etot, cursor);
    k_scatter<<<2048, 256, 0, stream>>>(s32, d32, E, N, cursor, esrc);

    k_cvtW1<<<divup(512 * 128, 256), 256, 0, stream>>>(W1, W1t);
    k_cvtW2<<<divup(128 * 64, 256), 256, 0, stream>>>(W2, W2t);

    k_gemm1<<<divup(N, 128), 256, 0, stream>>>(x, W1t, b1, N, t1, n1);
    k_conv<<<divup(N, 4), 256, 0, stream>>>(t1, n1, rp, esrc, N, nullptr, t2, n2);
    k_conv<<<divup(N, 4), 256, 0, stream>>>(t2, n2, rp, esrc, N, beta2, t1, nullptr);
    k_gemm2<<<divup(N, 128), 256, 0, stream>>>(t1, W2t, b2, N, out);
}

// Round 10
// 405.135 us; speedup vs baseline: 1.1263x; 1.0275x over previous
//
#include <hip/hip_runtime.h>
#include <math.h>

// ---------------------------------------------------------------------------
// AGNN round 10: conv index/norm chain batched per 64-edge chunk:
//  - one coalesced esrc load (64 idx/insn) + one nrmt gather (64/insn) per
//    chunk; per-round values distributed by __shfl (no cache-miss latency)
//  - row gathers remain 2-deep software-pipelined (r9, verified)
// gemm1 = r8 W-resident/A-streamed; rest identical to r9.
// ---------------------------------------------------------------------------

static inline int divup(int a, int b) { return (a + b - 1) / b; }

typedef __attribute__((ext_vector_type(8))) short short8;
typedef __attribute__((ext_vector_type(4))) float f32x4;
union U16 { uint4 u; short8 s; };

__device__ __forceinline__ unsigned bf16r(float f) {  // f32 -> bf16 bits, RNE
    unsigned u = __float_as_uint(f);
    return (u + 0x7FFFu + ((u >> 16) & 1u)) >> 16;
}
__device__ __forceinline__ unsigned pack2(float a, float b) {
    return bf16r(a) | (bf16r(b) << 16);
}
__device__ __forceinline__ float bflo(unsigned u) { return __uint_as_float(u << 16); }
__device__ __forceinline__ float bfhi(unsigned u) { return __uint_as_float(u & 0xFFFF0000u); }

// --- edge dtype detect / convert (+histogram fold) -------------------------
__global__ __launch_bounds__(64) void k_detect(const int* __restrict__ raw, int* flag) {
    int t = threadIdx.x;
    int v = raw[2 * t + 1];
    unsigned long long b = __ballot(v != 0);
    if (t == 0) *flag = (b == 0ULL) ? 1 : 0;  // 1 => int64 layout
}

__global__ __launch_bounds__(256) void k_cvt(const int* __restrict__ raw, int E,
                                             const int* __restrict__ flag,
                                             int* __restrict__ s32, int* __restrict__ d32,
                                             int* __restrict__ cnt) {
    int i = blockIdx.x * blockDim.x + threadIdx.x;
    if (i >= E) return;
    int s, d;
    if (*flag) {
        s = raw[2 * (size_t)i];
        d = raw[2 * ((size_t)E + i)];
    } else {
        s = raw[i];
        d = raw[(size_t)E + i];
    }
    s32[i] = s;
    d32[i] = d;
    atomicAdd(&cnt[d], 1);
}

// --- CSR scan (cnt + 1 self-loop per node) ---------------------------------
__global__ __launch_bounds__(1024) void k_scan1(const int* __restrict__ cnt, int N,
                                                int* __restrict__ rp, int* __restrict__ bsum) {
    __shared__ int sm[1024];
    int t = threadIdx.x;
    int i = blockIdx.x * 1024 + t;
    int v = (i < N) ? cnt[i] + 1 : 0;  // +1: self-loop
    sm[t] = v;
    __syncthreads();
#pragma unroll
    for (int off = 1; off < 1024; off <<= 1) {
        int u = (t >= off) ? sm[t - off] : 0;
        __syncthreads();
        sm[t] += u;
        __syncthreads();
    }
    if (i < N) rp[i] = sm[t] - v;  // exclusive
    if (t == 1023) bsum[blockIdx.x] = sm[t];
}

__global__ __launch_bounds__(64) void k_scan2(int* __restrict__ bsum, int nb) {
    if (threadIdx.x == 0) {
        int run = 0;
        for (int i = 0; i < nb; ++i) { int v = bsum[i]; bsum[i] = run; run += v; }
    }
}

__global__ __launch_bounds__(256) void k_scan3(int* __restrict__ rp, const int* __restrict__ bsum,
                                               int N, int Etot, int* __restrict__ cursor) {
    int i = blockIdx.x * blockDim.x + threadIdx.x;
    if (i < N) {
        int v = rp[i] + bsum[i >> 10];
        rp[i] = v;
        cursor[i] = v;
    } else if (i == N) {
        rp[N] = Etot;
    }
}

// --- XCD-partitioned scatter -----------------------------------------------
__global__ __launch_bounds__(256) void k_scatter(const int* __restrict__ s32,
                                                 const int* __restrict__ d32, int E, int N,
                                                 int* __restrict__ cursor,
                                                 int* __restrict__ esrc) {
    int b = blockIdx.x;
    int xcd = b & 7;
    int nstripe = gridDim.x >> 3;
    int stripe = b >> 3;
    int lo = (int)(((long long)xcd * N) >> 3);
    int hi = (int)(((long long)(xcd + 1) * N) >> 3);
    int Etot = E + N;
    for (int e = stripe * 256 + threadIdx.x; e < Etot; e += nstripe * 256) {
        int d = (e < E) ? d32[e] : (e - E);
        if (d < lo || d >= hi) continue;
        int s = (e < E) ? s32[e] : d;
        int pos = atomicAdd(&cursor[d], 1);
        esrc[pos] = s;
    }
}

// --- weight preconvert -----------------------------------------------------
__global__ __launch_bounds__(256) void k_cvtW1(const float* __restrict__ W1,
                                               unsigned short* __restrict__ W1t) {
    int i = blockIdx.x * 256 + threadIdx.x;
    if (i >= 512 * 128) return;
    int k = i >> 7, n = i & 127;
    W1t[n * 512 + k] = (unsigned short)bf16r(W1[i]);
}

__global__ __launch_bounds__(256) void k_cvtW2(const float* __restrict__ W2,
                                               unsigned short* __restrict__ W2t) {
    int i = blockIdx.x * 256 + threadIdx.x;
    if (i >= 128 * 64) return;
    int k = i >> 6, n = i & 63;
    W2t[n * 128 + k] = (unsigned short)bf16r(W2[i]);
}

// --- GEMM1: x_hat1/norm1 = normalize(relu(x @ W1 + b1)) --------------------
// W-resident / A-streamed (r8, verified). Zero barriers in K-loop.
#define XSW(c, off) ((off) ^ (((c) & 7) << 4))
__global__ __launch_bounds__(256) void k_gemm1(const float* __restrict__ x,
                                               const unsigned short* __restrict__ W1t,
                                               const float* __restrict__ b1, int N,
                                               unsigned short* __restrict__ xh1,
                                               float* __restrict__ n1) {
    __shared__ __align__(16) unsigned char lds[65536];
    const int tid = threadIdx.x;
    const int lane = tid & 63;
    const int lt = lane & 15, lg = lane >> 4;
    const int w = tid >> 6;
    const int row0 = blockIdx.x * 128;

    const float* xb[2];
#pragma unroll
    for (int rf = 0; rf < 2; ++rf) {
        int r = row0 + w * 32 + rf * 16 + lt;
        if (r > N - 1) r = N - 1;
        xb[rf] = x + (size_t)r * 512 + lg * 8;
    }

    f32x4 acc[2][8];
#pragma unroll
    for (int i = 0; i < 2; ++i)
#pragma unroll
        for (int j = 0; j < 8; ++j) acc[i][j] = (f32x4){0.f, 0.f, 0.f, 0.f};

    for (int ph = 0; ph < 2; ++ph) {
        const int kb = ph * 256;
        float4 ac[2][2], an[2][2];
#pragma unroll
        for (int rf = 0; rf < 2; ++rf) {
            ac[rf][0] = ((const float4*)(xb[rf] + kb))[0];
            ac[rf][1] = ((const float4*)(xb[rf] + kb))[1];
        }
        __syncthreads();
        {
            int c = tid >> 1, h = tid & 1;
            const uint4* wp = (const uint4*)(W1t + c * 512 + kb + h * 128);
            unsigned char* base = lds + c * 512;
#pragma unroll
            for (int i = 0; i < 16; ++i)
                *(uint4*)(base + XSW(c, h * 256 + i * 16)) = wp[i];
        }
        __syncthreads();

#pragma unroll
        for (int ks = 0; ks < 8; ++ks) {
            if (ks < 7) {
#pragma unroll
                for (int rf = 0; rf < 2; ++rf) {
                    an[rf][0] = ((const float4*)(xb[rf] + kb + (ks + 1) * 32))[0];
                    an[rf][1] = ((const float4*)(xb[rf] + kb + (ks + 1) * 32))[1];
                }
            }
            U16 af[2];
#pragma unroll
            for (int rf = 0; rf < 2; ++rf) {
                af[rf].u.x = pack2(ac[rf][0].x, ac[rf][0].y);
                af[rf].u.y = pack2(ac[rf][0].z, ac[rf][0].w);
                af[rf].u.z = pack2(ac[rf][1].x, ac[rf][1].y);
                af[rf].u.w = pack2(ac[rf][1].z, ac[rf][1].w);
            }
#pragma unroll
            for (int cf = 0; cf < 8; ++cf) {
                int col = cf * 16 + lt;
                U16 bf;
                bf.u = *(const uint4*)(lds + col * 512 + XSW(col, ks * 64 + lg * 16));
#pragma unroll
                for (int rf = 0; rf < 2; ++rf)
                    acc[rf][cf] = __builtin_amdgcn_mfma_f32_16x16x32_bf16(
                        af[rf].s, bf.s, acc[rf][cf], 0, 0, 0);
            }
            if (ks < 7) {
#pragma unroll
                for (int rf = 0; rf < 2; ++rf) {
                    ac[rf][0] = an[rf][0];
                    ac[rf][1] = an[rf][1];
                }
            }
        }
    }

    float bias[8];
#pragma unroll
    for (int cf = 0; cf < 8; ++cf) bias[cf] = b1[cf * 16 + lt];
    float* sc = (float*)lds;              // 64 rows x 132 f32 = 33792B
    unsigned char* pk = lds + 36864;      // 16KB packed bf16 bounce
#pragma unroll 1
    for (int p = 0; p < 2; ++p) {
        __syncthreads();
        if ((w >> 1) == p) {
#pragma unroll
            for (int rf = 0; rf < 2; ++rf)
#pragma unroll
                for (int reg = 0; reg < 4; ++reg) {
                    int rl = (w & 1) * 32 + rf * 16 + lg * 4 + reg;
#pragma unroll
                    for (int cf = 0; cf < 8; ++cf)
                        sc[rl * 132 + cf * 16 + lt] =
                            fmaxf(acc[rf][cf][reg] + bias[cf], 0.f);
                }
        }
        __syncthreads();
        {
            int rl = tid >> 2, q = tid & 3;
            int gr = row0 + p * 64 + rl;
            const float* rowp = sc + rl * 132 + q * 32;
            float v[32];
#pragma unroll
            for (int i = 0; i < 8; ++i) {
                float4 f = ((const float4*)rowp)[i];
                v[4 * i] = f.x; v[4 * i + 1] = f.y; v[4 * i + 2] = f.z; v[4 * i + 3] = f.w;
            }
            float s2 = 0.f;
#pragma unroll
            for (int i = 0; i < 32; ++i) s2 += v[i] * v[i];
            s2 += __shfl_xor(s2, 1, 64);
            s2 += __shfl_xor(s2, 2, 64);
            float nrm = sqrtf(s2);
            float rn = 1.0f / fmaxf(nrm, 1e-12f);
            uint4 o[4];
            unsigned* op = (unsigned*)o;
#pragma unroll
            for (int i = 0; i < 16; ++i)
                op[i] = pack2(v[2 * i] * rn, v[2 * i + 1] * rn);
            uint4* pd = (uint4*)(pk + rl * 256 + q * 64);
            pd[0] = o[0]; pd[1] = o[1]; pd[2] = o[2]; pd[3] = o[3];
            if (q == 0 && gr < N) n1[gr] = nrm;
        }
        __syncthreads();
#pragma unroll
        for (int j = 0; j < 4; ++j) {
            int boff = j * 4096 + tid * 16;
            int r = boff >> 8;
            int gr = row0 + p * 64 + r;
            if (gr < N)
                *(uint4*)((unsigned char*)xh1 + (size_t)gr * 256 + (boff & 255)) =
                    *(const uint4*)(pk + boff);
        }
    }
}

// --- AGNN conv: 16x4 geometry, chunked idx/norm batch + 2-deep row pipe ----
__global__ __launch_bounds__(256) void k_conv(const unsigned short* __restrict__ xh,
                                              const float* __restrict__ nrmt,
                                              const int* __restrict__ rp,
                                              const int* __restrict__ esrc, int N,
                                              const float* __restrict__ betap,
                                              unsigned short* __restrict__ outh,
                                              float* __restrict__ outn) {
    int node = (blockIdx.x * blockDim.x + threadIdx.x) >> 6;
    if (node >= N) return;
    int lane = threadIdx.x & 63;
    int t = lane & 15, g = lane >> 4;
    float beta = betap ? *betap : 1.0f;

    uint4 hdu = *(const uint4*)&xh[(size_t)node * 128 + 8 * t];
    float hd[8];
    hd[0] = bflo(hdu.x); hd[1] = bfhi(hdu.x);
    hd[2] = bflo(hdu.y); hd[3] = bfhi(hdu.y);
    hd[4] = bflo(hdu.z); hd[5] = bfhi(hdu.z);
    hd[6] = bflo(hdu.w); hd[7] = bfhi(hdu.w);

    int e0 = rp[node], e1 = rp[node + 1];
    float acc[8] = {0.f, 0.f, 0.f, 0.f, 0.f, 0.f, 0.f, 0.f};
    float ssum = 0.f;

    for (int cs = e0; cs < e1; cs += 64) {
        // batch: 64 edge indices coalesced, 64 norms in one gather
        int el = cs + lane;
        int sidx = esrc[(el < e1) ? el : e0];
        float nsl = nrmt[sidx];
        int R = e1 - cs;                 // edges left in this chunk
        if (R > 64) R = 64;
        int nr = (R + 3) >> 2;           // rounds in chunk (wave-uniform)

        // prologue: round-0 row in flight
        int sA = __shfl(sidx, g, 64);
        float nsA = __shfl(nsl, g, 64);
        uint4 rowA = *(const uint4*)&xh[(size_t)sA * 128 + 8 * t];

        for (int r = 0; r < nr; ++r) {
            const bool hasNext = (r + 1) < nr;  // wave-uniform
            uint4 rowB;
            float nsB = 0.f;
            if (hasNext) {
                int sB = __shfl(sidx, 4 * (r + 1) + g, 64);
                nsB = __shfl(nsl, 4 * (r + 1) + g, 64);
                rowB = *(const uint4*)&xh[(size_t)sB * 128 + 8 * t];
            }
            float v[8];
            v[0] = bflo(rowA.x); v[1] = bfhi(rowA.x);
            v[2] = bflo(rowA.y); v[3] = bfhi(rowA.y);
            v[4] = bflo(rowA.z); v[5] = bfhi(rowA.z);
            v[6] = bflo(rowA.w); v[7] = bfhi(rowA.w);
            float p = 0.f;
#pragma unroll
            for (int j = 0; j < 8; ++j) p += v[j] * hd[j];
            p += __shfl_xor(p, 1, 64);
            p += __shfl_xor(p, 2, 64);
            p += __shfl_xor(p, 4, 64);
            p += __shfl_xor(p, 8, 64);
            int e = cs + 4 * r + g;
            float w = (e < e1) ? __expf(p * beta) : 0.f;
            float wn = w * nsA;
            ssum += w;
#pragma unroll
            for (int j = 0; j < 8; ++j) acc[j] += wn * v[j];
            if (hasNext) {
                rowA = rowB;
                nsA = nsB;
            }
        }
    }
#pragma unroll
    for (int j = 0; j < 8; ++j) {
        acc[j] += __shfl_xor(acc[j], 16, 64);
        acc[j] += __shfl_xor(acc[j], 32, 64);
    }
    ssum += __shfl_xor(ssum, 16, 64);
    ssum += __shfl_xor(ssum, 32, 64);
    float r = 1.0f / ssum;

    if (outn == nullptr) {
        if (g == 0) {
            uint4 q;
            q.x = pack2(acc[0] * r, acc[1] * r);
            q.y = pack2(acc[2] * r, acc[3] * r);
            q.z = pack2(acc[4] * r, acc[5] * r);
            q.w = pack2(acc[6] * r, acc[7] * r);
            *(uint4*)&outh[(size_t)node * 128 + 8 * t] = q;
        }
    } else {
        float o[8];
        float s2 = 0.f;
#pragma unroll
        for (int j = 0; j < 8; ++j) { o[j] = acc[j] * r; s2 += o[j] * o[j]; }
        s2 += __shfl_xor(s2, 1, 64);
        s2 += __shfl_xor(s2, 2, 64);
        s2 += __shfl_xor(s2, 4, 64);
        s2 += __shfl_xor(s2, 8, 64);
        float nn = sqrtf(s2);
        float rn = 1.0f / fmaxf(nn, 1e-12f);
        if (g == 0) {
            uint4 q;
            q.x = pack2(o[0] * rn, o[1] * rn);
            q.y = pack2(o[2] * rn, o[3] * rn);
            q.z = pack2(o[4] * rn, o[5] * rn);
            q.w = pack2(o[6] * rn, o[7] * rn);
            *(uint4*)&outh[(size_t)node * 128 + 8 * t] = q;
            if (t == 0) outn[node] = nn;
        }
    }
}

// --- GEMM2 (MFMA) + fused log_softmax --------------------------------------
#define G2_ASTRIDE 272
__global__ __launch_bounds__(256) void k_gemm2(const unsigned short* __restrict__ h,
                                               const unsigned short* __restrict__ W2t,
                                               const float* __restrict__ b2, int N,
                                               float* __restrict__ out) {
    __shared__ __align__(16) unsigned char As[128 * G2_ASTRIDE];
    __shared__ __align__(16) unsigned char Bs[64 * G2_ASTRIDE];
    const int tid = threadIdx.x;
    const int lane = tid & 63;
    const int lt = lane & 15, lg = lane >> 4;
    const int wid = tid >> 6;
    const int row0 = blockIdx.x * 128;

    {
        int arow = tid >> 1, ahalf = tid & 1;
        const uint4* src = (const uint4*)(h + (size_t)(row0 + arow) * 128 + ahalf * 64);
        unsigned char* ab = As + arow * G2_ASTRIDE + ahalf * 128;
#pragma unroll
        for (int i = 0; i < 8; ++i) ((uint4*)ab)[i] = src[i];
        int brow = tid >> 2, bq = tid & 3;
        const uint4* bs = (const uint4*)(W2t + (size_t)brow * 128 + bq * 32);
        unsigned char* bb = Bs + brow * G2_ASTRIDE + bq * 64;
#pragma unroll
        for (int i = 0; i < 4; ++i) ((uint4*)bb)[i] = bs[i];
    }
    __syncthreads();

    f32x4 acc[2][4];
#pragma unroll
    for (int i = 0; i < 2; ++i)
#pragma unroll
        for (int j = 0; j < 4; ++j) acc[i][j] = (f32x4){0.f, 0.f, 0.f, 0.f};

#pragma unroll
    for (int sub = 0; sub < 4; ++sub) {
        U16 af[2], bf[4];
#pragma unroll
        for (int mi = 0; mi < 2; ++mi)
            af[mi].u = *(const uint4*)(As + (wid * 32 + mi * 16 + lt) * G2_ASTRIDE + sub * 64 + lg * 16);
#pragma unroll
        for (int ni = 0; ni < 4; ++ni)
            bf[ni].u = *(const uint4*)(Bs + (ni * 16 + lt) * G2_ASTRIDE + sub * 64 + lg * 16);
#pragma unroll
        for (int mi = 0; mi < 2; ++mi)
#pragma unroll
            for (int ni = 0; ni < 4; ++ni)
                acc[mi][ni] = __builtin_amdgcn_mfma_f32_16x16x32_bf16(
                    af[mi].s, bf[ni].s, acc[mi][ni], 0, 0, 0);
    }

    float bias[4];
#pragma unroll
    for (int ni = 0; ni < 4; ++ni) bias[ni] = b2[ni * 16 + lt];

#pragma unroll
    for (int mi = 0; mi < 2; ++mi) {
#pragma unroll
        for (int reg = 0; reg < 4; ++reg) {
            int row = row0 + wid * 32 + mi * 16 + lg * 4 + reg;
            if (row < N) {
                float v[4];
#pragma unroll
                for (int ni = 0; ni < 4; ++ni) v[ni] = acc[mi][ni][reg] + bias[ni];
                float m = fmaxf(fmaxf(v[0], v[1]), fmaxf(v[2], v[3]));
                m = fmaxf(m, __shfl_xor(m, 1, 64));
                m = fmaxf(m, __shfl_xor(m, 2, 64));
                m = fmaxf(m, __shfl_xor(m, 4, 64));
                m = fmaxf(m, __shfl_xor(m, 8, 64));
                float s = __expf(v[0] - m) + __expf(v[1] - m) +
                          __expf(v[2] - m) + __expf(v[3] - m);
                s += __shfl_xor(s, 1, 64);
                s += __shfl_xor(s, 2, 64);
                s += __shfl_xor(s, 4, 64);
                s += __shfl_xor(s, 8, 64);
                float lg2 = logf(s);
#pragma unroll
                for (int ni = 0; ni < 4; ++ni)
                    out[(size_t)row * 64 + ni * 16 + lt] = v[ni] - m - lg2;
            }
        }
    }
}

// ---------------------------------------------------------------------------
extern "C" void kernel_launch(void* const* d_in, const int* in_sizes, int n_in,
                              void* d_out, int out_size, void* d_ws, size_t ws_size,
                              hipStream_t stream) {
    const float* x     = (const float*)d_in[0];
    const int*   ei    = (const int*)d_in[1];
    const float* W1    = (const float*)d_in[2];
    const float* b1    = (const float*)d_in[3];
    const float* beta2 = (const float*)d_in[4];
    const float* W2    = (const float*)d_in[5];
    const float* b2    = (const float*)d_in[6];
    float* out = (float*)d_out;

    const int N = in_sizes[0] / 512;
    const int E = in_sizes[1] / 2;
    const int Etot = E + N;

    char* ws = (char*)d_ws;
    size_t off = 0;
    auto alloc = [&](size_t bytes) -> void* {
        void* p = ws + off;
        off = (off + bytes + 511) & ~(size_t)511;
        return p;
    };
    unsigned short* t1 = (unsigned short*)alloc((size_t)N * 128 * 2);  // x_hat1 / h3
    unsigned short* t2 = (unsigned short*)alloc((size_t)N * 128 * 2);  // x_hat2
    float* n1   = (float*)alloc((size_t)N * 4);
    float* n2   = (float*)alloc((size_t)N * 4);
    int* cnt    = (int*)alloc((size_t)N * 4);
    int* rp     = (int*)alloc((size_t)(N + 1) * 4);
    int* cursor = (int*)alloc((size_t)N * 4);
    int* bsum   = (int*)alloc(4096);
    int* flag   = (int*)alloc(512);
    unsigned short* W1t = (unsigned short*)alloc(512 * 128 * 2);
    unsigned short* W2t = (unsigned short*)alloc(128 * 64 * 2);
    int* s32    = (int*)alloc((size_t)E * 4);
    int* d32    = (int*)alloc((size_t)E * 4);
    int* esrc   = (int*)alloc((size_t)Etot * 4);
    (void)ws_size; (void)n_in; (void)out_size;

    (void)hipMemsetAsync(cnt, 0, (size_t)N * 4, stream);

    k_detect<<<1, 64, 0, stream>>>(ei, flag);
    k_cvt<<<divup(E, 256), 256, 0, stream>>>(ei, E, flag, s32, d32, cnt);
    int nb = divup(N, 1024);
    k_scan1<<<nb, 1024, 0, stream>>>(cnt, N, rp, bsum);
    k_scan2<<<1, 64, 0, stream>>>(bsum, nb);
    k_scan3<<<divup(N + 1, 256), 256, 0, stream>>>(rp, bsum, N, Etot, cursor);
    k_scatter<<<2048, 256, 0, stream>>>(s32, d32, E, N, cursor, esrc);

    k_cvtW1<<<divup(512 * 128, 256), 256, 0, stream>>>(W1, W1t);
    k_cvtW2<<<divup(128 * 64, 256), 256, 0, stream>>>(W2, W2t);

    k_gemm1<<<divup(N, 128), 256, 0, stream>>>(x, W1t, b1, N, t1, n1);
    k_conv<<<divup(N, 4), 256, 0, stream>>>(t1, n1, rp, esrc, N, nullptr, t2, n2);
    k_conv<<<divup(N, 4), 256, 0, stream>>>(t2, n2, rp, esrc, N, beta2, t1, nullptr);
    k_gemm2<<<divup(N, 128), 256, 0, stream>>>(t1, W2t, b2, N, out);
}

// Round 11
// 405.114 us; speedup vs baseline: 1.1263x; 1.0000x over previous
//
#include <hip/hip_runtime.h>
#include <math.h>

// ---------------------------------------------------------------------------
// AGNN round 11: gemm1 A-stream made phase-deep:
//  - whole 256-k phase of A held in regs (areg[2][8][2] f4 = 128 VGPR,
//    statically indexed), issued as one 32-load burst -> in-wave MLP covers
//    ~900cy HBM latency (r10 counters: prefetch depth 1 = 150cy << 900cy,
//    2 waves/SIMD -> 116us at 0.87 TB/s effective)
//  - phase-1 refill of areg[ks] issued immediately after phase-0 consumes it
//    (one full phase ~1200cy ahead of use)
// conv = r10 chunked+pipelined (verified); rest identical to r10.
// ---------------------------------------------------------------------------

static inline int divup(int a, int b) { return (a + b - 1) / b; }

typedef __attribute__((ext_vector_type(8))) short short8;
typedef __attribute__((ext_vector_type(4))) float f32x4;
union U16 { uint4 u; short8 s; };

__device__ __forceinline__ unsigned bf16r(float f) {  // f32 -> bf16 bits, RNE
    unsigned u = __float_as_uint(f);
    return (u + 0x7FFFu + ((u >> 16) & 1u)) >> 16;
}
__device__ __forceinline__ unsigned pack2(float a, float b) {
    return bf16r(a) | (bf16r(b) << 16);
}
__device__ __forceinline__ float bflo(unsigned u) { return __uint_as_float(u << 16); }
__device__ __forceinline__ float bfhi(unsigned u) { return __uint_as_float(u & 0xFFFF0000u); }

// --- edge dtype detect / convert (+histogram fold) -------------------------
__global__ __launch_bounds__(64) void k_detect(const int* __restrict__ raw, int* flag) {
    int t = threadIdx.x;
    int v = raw[2 * t + 1];
    unsigned long long b = __ballot(v != 0);
    if (t == 0) *flag = (b == 0ULL) ? 1 : 0;  // 1 => int64 layout
}

__global__ __launch_bounds__(256) void k_cvt(const int* __restrict__ raw, int E,
                                             const int* __restrict__ flag,
                                             int* __restrict__ s32, int* __restrict__ d32,
                                             int* __restrict__ cnt) {
    int i = blockIdx.x * blockDim.x + threadIdx.x;
    if (i >= E) return;
    int s, d;
    if (*flag) {
        s = raw[2 * (size_t)i];
        d = raw[2 * ((size_t)E + i)];
    } else {
        s = raw[i];
        d = raw[(size_t)E + i];
    }
    s32[i] = s;
    d32[i] = d;
    atomicAdd(&cnt[d], 1);
}

// --- CSR scan (cnt + 1 self-loop per node) ---------------------------------
__global__ __launch_bounds__(1024) void k_scan1(const int* __restrict__ cnt, int N,
                                                int* __restrict__ rp, int* __restrict__ bsum) {
    __shared__ int sm[1024];
    int t = threadIdx.x;
    int i = blockIdx.x * 1024 + t;
    int v = (i < N) ? cnt[i] + 1 : 0;  // +1: self-loop
    sm[t] = v;
    __syncthreads();
#pragma unroll
    for (int off = 1; off < 1024; off <<= 1) {
        int u = (t >= off) ? sm[t - off] : 0;
        __syncthreads();
        sm[t] += u;
        __syncthreads();
    }
    if (i < N) rp[i] = sm[t] - v;  // exclusive
    if (t == 1023) bsum[blockIdx.x] = sm[t];
}

__global__ __launch_bounds__(64) void k_scan2(int* __restrict__ bsum, int nb) {
    if (threadIdx.x == 0) {
        int run = 0;
        for (int i = 0; i < nb; ++i) { int v = bsum[i]; bsum[i] = run; run += v; }
    }
}

__global__ __launch_bounds__(256) void k_scan3(int* __restrict__ rp, const int* __restrict__ bsum,
                                               int N, int Etot, int* __restrict__ cursor) {
    int i = blockIdx.x * blockDim.x + threadIdx.x;
    if (i < N) {
        int v = rp[i] + bsum[i >> 10];
        rp[i] = v;
        cursor[i] = v;
    } else if (i == N) {
        rp[N] = Etot;
    }
}

// --- XCD-partitioned scatter -----------------------------------------------
__global__ __launch_bounds__(256) void k_scatter(const int* __restrict__ s32,
                                                 const int* __restrict__ d32, int E, int N,
                                                 int* __restrict__ cursor,
                                                 int* __restrict__ esrc) {
    int b = blockIdx.x;
    int xcd = b & 7;
    int nstripe = gridDim.x >> 3;
    int stripe = b >> 3;
    int lo = (int)(((long long)xcd * N) >> 3);
    int hi = (int)(((long long)(xcd + 1) * N) >> 3);
    int Etot = E + N;
    for (int e = stripe * 256 + threadIdx.x; e < Etot; e += nstripe * 256) {
        int d = (e < E) ? d32[e] : (e - E);
        if (d < lo || d >= hi) continue;
        int s = (e < E) ? s32[e] : d;
        int pos = atomicAdd(&cursor[d], 1);
        esrc[pos] = s;
    }
}

// --- weight preconvert -----------------------------------------------------
__global__ __launch_bounds__(256) void k_cvtW1(const float* __restrict__ W1,
                                               unsigned short* __restrict__ W1t) {
    int i = blockIdx.x * 256 + threadIdx.x;
    if (i >= 512 * 128) return;
    int k = i >> 7, n = i & 127;
    W1t[n * 512 + k] = (unsigned short)bf16r(W1[i]);
}

__global__ __launch_bounds__(256) void k_cvtW2(const float* __restrict__ W2,
                                               unsigned short* __restrict__ W2t) {
    int i = blockIdx.x * 256 + threadIdx.x;
    if (i >= 128 * 64) return;
    int k = i >> 6, n = i & 63;
    W2t[n * 128 + k] = (unsigned short)bf16r(W2[i]);
}

// --- GEMM1: x_hat1/norm1 = normalize(relu(x @ W1 + b1)) --------------------
// W-resident / A-streamed, phase-deep A prefetch (128 VGPR of A in flight).
#define XSW(c, off) ((off) ^ (((c) & 7) << 4))
__global__ __launch_bounds__(256) void k_gemm1(const float* __restrict__ x,
                                               const unsigned short* __restrict__ W1t,
                                               const float* __restrict__ b1, int N,
                                               unsigned short* __restrict__ xh1,
                                               float* __restrict__ n1) {
    __shared__ __align__(16) unsigned char lds[65536];
    const int tid = threadIdx.x;
    const int lane = tid & 63;
    const int lt = lane & 15, lg = lane >> 4;
    const int w = tid >> 6;
    const int row0 = blockIdx.x * 128;

    const float* xb[2];
#pragma unroll
    for (int rf = 0; rf < 2; ++rf) {
        int r = row0 + w * 32 + rf * 16 + lt;
        if (r > N - 1) r = N - 1;
        xb[rf] = x + (size_t)r * 512 + lg * 8;
    }

    // full-phase A register file (statically indexed only)
    float4 areg[2][8][2];
#pragma unroll
    for (int ks = 0; ks < 8; ++ks)
#pragma unroll
        for (int rf = 0; rf < 2; ++rf) {
            areg[rf][ks][0] = ((const float4*)(xb[rf] + ks * 32))[0];
            areg[rf][ks][1] = ((const float4*)(xb[rf] + ks * 32))[1];
        }

    // stage W phase 0
    {
        int c = tid >> 1, h = tid & 1;
        const uint4* wp = (const uint4*)(W1t + c * 512 + h * 128);
        unsigned char* base = lds + c * 512;
#pragma unroll
        for (int i = 0; i < 16; ++i)
            *(uint4*)(base + XSW(c, h * 256 + i * 16)) = wp[i];
    }
    __syncthreads();

    f32x4 acc[2][8];
#pragma unroll
    for (int i = 0; i < 2; ++i)
#pragma unroll
        for (int j = 0; j < 8; ++j) acc[i][j] = (f32x4){0.f, 0.f, 0.f, 0.f};

#pragma unroll
    for (int ph = 0; ph < 2; ++ph) {
#pragma unroll
        for (int ks = 0; ks < 8; ++ks) {
            U16 af[2];
#pragma unroll
            for (int rf = 0; rf < 2; ++rf) {
                af[rf].u.x = pack2(areg[rf][ks][0].x, areg[rf][ks][0].y);
                af[rf].u.y = pack2(areg[rf][ks][0].z, areg[rf][ks][0].w);
                af[rf].u.z = pack2(areg[rf][ks][1].x, areg[rf][ks][1].y);
                af[rf].u.w = pack2(areg[rf][ks][1].z, areg[rf][ks][1].w);
            }
            if (ph == 0) {  // refill this slot with phase-1 data (used in ~8 ks)
#pragma unroll
                for (int rf = 0; rf < 2; ++rf) {
                    areg[rf][ks][0] = ((const float4*)(xb[rf] + 256 + ks * 32))[0];
                    areg[rf][ks][1] = ((const float4*)(xb[rf] + 256 + ks * 32))[1];
                }
            }
#pragma unroll
            for (int cf = 0; cf < 8; ++cf) {
                int col = cf * 16 + lt;
                U16 bf;
                bf.u = *(const uint4*)(lds + col * 512 + XSW(col, ks * 64 + lg * 16));
#pragma unroll
                for (int rf = 0; rf < 2; ++rf)
                    acc[rf][cf] = __builtin_amdgcn_mfma_f32_16x16x32_bf16(
                        af[rf].s, bf.s, acc[rf][cf], 0, 0, 0);
            }
        }
        if (ph == 0) {  // stage W phase 1
            __syncthreads();
            {
                int c = tid >> 1, h = tid & 1;
                const uint4* wp = (const uint4*)(W1t + c * 512 + 256 + h * 128);
                unsigned char* base = lds + c * 512;
#pragma unroll
                for (int i = 0; i < 16; ++i)
                    *(uint4*)(base + XSW(c, h * 256 + i * 16)) = wp[i];
            }
            __syncthreads();
        }
    }

    // epilogue: bias+relu -> LDS rows -> norm -> pack -> LDS bounce -> dense
    float bias[8];
#pragma unroll
    for (int cf = 0; cf < 8; ++cf) bias[cf] = b1[cf * 16 + lt];
    float* sc = (float*)lds;              // 64 rows x 132 f32 = 33792B
    unsigned char* pk = lds + 36864;      // 16KB packed bf16 bounce
#pragma unroll 1
    for (int p = 0; p < 2; ++p) {
        __syncthreads();
        if ((w >> 1) == p) {
#pragma unroll
            for (int rf = 0; rf < 2; ++rf)
#pragma unroll
                for (int reg = 0; reg < 4; ++reg) {
                    int rl = (w & 1) * 32 + rf * 16 + lg * 4 + reg;
#pragma unroll
                    for (int cf = 0; cf < 8; ++cf)
                        sc[rl * 132 + cf * 16 + lt] =
                            fmaxf(acc[rf][cf][reg] + bias[cf], 0.f);
                }
        }
        __syncthreads();
        {
            int rl = tid >> 2, q = tid & 3;
            int gr = row0 + p * 64 + rl;
            const float* rowp = sc + rl * 132 + q * 32;
            float v[32];
#pragma unroll
            for (int i = 0; i < 8; ++i) {
                float4 f = ((const float4*)rowp)[i];
                v[4 * i] = f.x; v[4 * i + 1] = f.y; v[4 * i + 2] = f.z; v[4 * i + 3] = f.w;
            }
            float s2 = 0.f;
#pragma unroll
            for (int i = 0; i < 32; ++i) s2 += v[i] * v[i];
            s2 += __shfl_xor(s2, 1, 64);
            s2 += __shfl_xor(s2, 2, 64);
            float nrm = sqrtf(s2);
            float rn = 1.0f / fmaxf(nrm, 1e-12f);
            uint4 o[4];
            unsigned* op = (unsigned*)o;
#pragma unroll
            for (int i = 0; i < 16; ++i)
                op[i] = pack2(v[2 * i] * rn, v[2 * i + 1] * rn);
            uint4* pd = (uint4*)(pk + rl * 256 + q * 64);
            pd[0] = o[0]; pd[1] = o[1]; pd[2] = o[2]; pd[3] = o[3];
            if (q == 0 && gr < N) n1[gr] = nrm;
        }
        __syncthreads();
#pragma unroll
        for (int j = 0; j < 4; ++j) {
            int boff = j * 4096 + tid * 16;
            int r = boff >> 8;
            int gr = row0 + p * 64 + r;
            if (gr < N)
                *(uint4*)((unsigned char*)xh1 + (size_t)gr * 256 + (boff & 255)) =
                    *(const uint4*)(pk + boff);
        }
    }
}

// --- AGNN conv: 16x4 geometry, chunked idx/norm batch + 2-deep row pipe ----
__global__ __launch_bounds__(256) void k_conv(const unsigned short* __restrict__ xh,
                                              const float* __restrict__ nrmt,
                                              const int* __restrict__ rp,
                                              const int* __restrict__ esrc, int N,
                                              const float* __restrict__ betap,
                                              unsigned short* __restrict__ outh,
                                              float* __restrict__ outn) {
    int node = (blockIdx.x * blockDim.x + threadIdx.x) >> 6;
    if (node >= N) return;
    int lane = threadIdx.x & 63;
    int t = lane & 15, g = lane >> 4;
    float beta = betap ? *betap : 1.0f;

    uint4 hdu = *(const uint4*)&xh[(size_t)node * 128 + 8 * t];
    float hd[8];
    hd[0] = bflo(hdu.x); hd[1] = bfhi(hdu.x);
    hd[2] = bflo(hdu.y); hd[3] = bfhi(hdu.y);
    hd[4] = bflo(hdu.z); hd[5] = bfhi(hdu.z);
    hd[6] = bflo(hdu.w); hd[7] = bfhi(hdu.w);

    int e0 = rp[node], e1 = rp[node + 1];
    float acc[8] = {0.f, 0.f, 0.f, 0.f, 0.f, 0.f, 0.f, 0.f};
    float ssum = 0.f;

    for (int cs = e0; cs < e1; cs += 64) {
        int el = cs + lane;
        int sidx = esrc[(el < e1) ? el : e0];
        float nsl = nrmt[sidx];
        int R = e1 - cs;
        if (R > 64) R = 64;
        int nr = (R + 3) >> 2;

        int sA = __shfl(sidx, g, 64);
        float nsA = __shfl(nsl, g, 64);
        uint4 rowA = *(const uint4*)&xh[(size_t)sA * 128 + 8 * t];

        for (int r = 0; r < nr; ++r) {
            const bool hasNext = (r + 1) < nr;
            uint4 rowB;
            float nsB = 0.f;
            if (hasNext) {
                int sB = __shfl(sidx, 4 * (r + 1) + g, 64);
                nsB = __shfl(nsl, 4 * (r + 1) + g, 64);
                rowB = *(const uint4*)&xh[(size_t)sB * 128 + 8 * t];
            }
            float v[8];
            v[0] = bflo(rowA.x); v[1] = bfhi(rowA.x);
            v[2] = bflo(rowA.y); v[3] = bfhi(rowA.y);
            v[4] = bflo(rowA.z); v[5] = bfhi(rowA.z);
            v[6] = bflo(rowA.w); v[7] = bfhi(rowA.w);
            float p = 0.f;
#pragma unroll
            for (int j = 0; j < 8; ++j) p += v[j] * hd[j];
            p += __shfl_xor(p, 1, 64);
            p += __shfl_xor(p, 2, 64);
            p += __shfl_xor(p, 4, 64);
            p += __shfl_xor(p, 8, 64);
            int e = cs + 4 * r + g;
            float w = (e < e1) ? __expf(p * beta) : 0.f;
            float wn = w * nsA;
            ssum += w;
#pragma unroll
            for (int j = 0; j < 8; ++j) acc[j] += wn * v[j];
            if (hasNext) {
                rowA = rowB;
                nsA = nsB;
            }
        }
    }
#pragma unroll
    for (int j = 0; j < 8; ++j) {
        acc[j] += __shfl_xor(acc[j], 16, 64);
        acc[j] += __shfl_xor(acc[j], 32, 64);
    }
    ssum += __shfl_xor(ssum, 16, 64);
    ssum += __shfl_xor(ssum, 32, 64);
    float r = 1.0f / ssum;

    if (outn == nullptr) {
        if (g == 0) {
            uint4 q;
            q.x = pack2(acc[0] * r, acc[1] * r);
            q.y = pack2(acc[2] * r, acc[3] * r);
            q.z = pack2(acc[4] * r, acc[5] * r);
            q.w = pack2(acc[6] * r, acc[7] * r);
            *(uint4*)&outh[(size_t)node * 128 + 8 * t] = q;
        }
    } else {
        float o[8];
        float s2 = 0.f;
#pragma unroll
        for (int j = 0; j < 8; ++j) { o[j] = acc[j] * r; s2 += o[j] * o[j]; }
        s2 += __shfl_xor(s2, 1, 64);
        s2 += __shfl_xor(s2, 2, 64);
        s2 += __shfl_xor(s2, 4, 64);
        s2 += __shfl_xor(s2, 8, 64);
        float nn = sqrtf(s2);
        float rn = 1.0f / fmaxf(nn, 1e-12f);
        if (g == 0) {
            uint4 q;
            q.x = pack2(o[0] * rn, o[1] * rn);
            q.y = pack2(o[2] * rn, o[3] * rn);
            q.z = pack2(o[4] * rn, o[5] * rn);
            q.w = pack2(o[6] * rn, o[7] * rn);
            *(uint4*)&outh[(size_t)node * 128 + 8 * t] = q;
            if (t == 0) outn[node] = nn;
        }
    }
}

// --- GEMM2 (MFMA) + fused log_softmax --------------------------------------
#define G2_ASTRIDE 272
__global__ __launch_bounds__(256) void k_gemm2(const unsigned short* __restrict__ h,
                                               const unsigned short* __restrict__ W2t,
                                               const float* __restrict__ b2, int N,
                                               float* __restrict__ out) {
    __shared__ __align__(16) unsigned char As[128 * G2_ASTRIDE];
    __shared__ __align__(16) unsigned char Bs[64 * G2_ASTRIDE];
    const int tid = threadIdx.x;
    const int lane = tid & 63;
    const int lt = lane & 15, lg = lane >> 4;
    const int wid = tid >> 6;
    const int row0 = blockIdx.x * 128;

    {
        int arow = tid >> 1, ahalf = tid & 1;
        const uint4* src = (const uint4*)(h + (size_t)(row0 + arow) * 128 + ahalf * 64);
        unsigned char* ab = As + arow * G2_ASTRIDE + ahalf * 128;
#pragma unroll
        for (int i = 0; i < 8; ++i) ((uint4*)ab)[i] = src[i];
        int brow = tid >> 2, bq = tid & 3;
        const uint4* bs = (const uint4*)(W2t + (size_t)brow * 128 + bq * 32);
        unsigned char* bb = Bs + brow * G2_ASTRIDE + bq * 64;
#pragma unroll
        for (int i = 0; i < 4; ++i) ((uint4*)bb)[i] = bs[i];
    }
    __syncthreads();

    f32x4 acc[2][4];
#pragma unroll
    for (int i = 0; i < 2; ++i)
#pragma unroll
        for (int j = 0; j < 4; ++j) acc[i][j] = (f32x4){0.f, 0.f, 0.f, 0.f};

#pragma unroll
    for (int sub = 0; sub < 4; ++sub) {
        U16 af[2], bf[4];
#pragma unroll
        for (int mi = 0; mi < 2; ++mi)
            af[mi].u = *(const uint4*)(As + (wid * 32 + mi * 16 + lt) * G2_ASTRIDE + sub * 64 + lg * 16);
#pragma unroll
        for (int ni = 0; ni < 4; ++ni)
            bf[ni].u = *(const uint4*)(Bs + (ni * 16 + lt) * G2_ASTRIDE + sub * 64 + lg * 16);
#pragma unroll
        for (int mi = 0; mi < 2; ++mi)
#pragma unroll
            for (int ni = 0; ni < 4; ++ni)
                acc[mi][ni] = __builtin_amdgcn_mfma_f32_16x16x32_bf16(
                    af[mi].s, bf[ni].s, acc[mi][ni], 0, 0, 0);
    }

    float bias[4];
#pragma unroll
    for (int ni = 0; ni < 4; ++ni) bias[ni] = b2[ni * 16 + lt];

#pragma unroll
    for (int mi = 0; mi < 2; ++mi) {
#pragma unroll
        for (int reg = 0; reg < 4; ++reg) {
            int row = row0 + wid * 32 + mi * 16 + lg * 4 + reg;
            if (row < N) {
                float v[4];
#pragma unroll
                for (int ni = 0; ni < 4; ++ni) v[ni] = acc[mi][ni][reg] + bias[ni];
                float m = fmaxf(fmaxf(v[0], v[1]), fmaxf(v[2], v[3]));
                m = fmaxf(m, __shfl_xor(m, 1, 64));
                m = fmaxf(m, __shfl_xor(m, 2, 64));
                m = fmaxf(m, __shfl_xor(m, 4, 64));
                m = fmaxf(m, __shfl_xor(m, 8, 64));
                float s = __expf(v[0] - m) + __expf(v[1] - m) +
                          __expf(v[2] - m) + __expf(v[3] - m);
                s += __shfl_xor(s, 1, 64);
                s += __shfl_xor(s, 2, 64);
                s += __shfl_xor(s, 4, 64);
                s += __shfl_xor(s, 8, 64);
                float lg2 = logf(s);
#pragma unroll
                for (int ni = 0; ni < 4; ++ni)
                    out[(size_t)row * 64 + ni * 16 + lt] = v[ni] - m - lg2;
            }
        }
    }
}

// ---------------------------------------------------------------------------
extern "C" void kernel_launch(void* const* d_in, const int* in_sizes, int n_in,
                              void* d_out, int out_size, void* d_ws, size_t ws_size,
                              hipStream_t stream) {
    const float* x     = (const float*)d_in[0];
    const int*   ei    = (const int*)d_in[1];
    const float* W1    = (const float*)d_in[2];
    const float* b1    = (const float*)d_in[3];
    const float* beta2 = (const float*)d_in[4];
    const float* W2    = (const float*)d_in[5];
    const float* b2    = (const float*)d_in[6];
    float* out = (float*)d_out;

    const int N = in_sizes[0] / 512;
    const int E = in_sizes[1] / 2;
    const int Etot = E + N;

    char* ws = (char*)d_ws;
    size_t off = 0;
    auto alloc = [&](size_t bytes) -> void* {
        void* p = ws + off;
        off = (off + bytes + 511) & ~(size_t)511;
        return p;
    };
    unsigned short* t1 = (unsigned short*)alloc((size_t)N * 128 * 2);  // x_hat1 / h3
    unsigned short* t2 = (unsigned short*)alloc((size_t)N * 128 * 2);  // x_hat2
    float* n1   = (float*)alloc((size_t)N * 4);
    float* n2   = (float*)alloc((size_t)N * 4);
    int* cnt    = (int*)alloc((size_t)N * 4);
    int* rp     = (int*)alloc((size_t)(N + 1) * 4);
    int* cursor = (int*)alloc((size_t)N * 4);
    int* bsum   = (int*)alloc(4096);
    int* flag   = (int*)alloc(512);
    unsigned short* W1t = (unsigned short*)alloc(512 * 128 * 2);
    unsigned short* W2t = (unsigned short*)alloc(128 * 64 * 2);
    int* s32    = (int*)alloc((size_t)E * 4);
    int* d32    = (int*)alloc((size_t)E * 4);
    int* esrc   = (int*)alloc((size_t)Etot * 4);
    (void)ws_size; (void)n_in; (void)out_size;

    (void)hipMemsetAsync(cnt, 0, (size_t)N * 4, stream);

    k_detect<<<1, 64, 0, stream>>>(ei, flag);
    k_cvt<<<divup(E, 256), 256, 0, stream>>>(ei, E, flag, s32, d32, cnt);
    int nb = divup(N, 1024);
    k_scan1<<<nb, 1024, 0, stream>>>(cnt, N, rp, bsum);
    k_scan2<<<1, 64, 0, stream>>>(bsum, nb);
    k_scan3<<<divup(N + 1, 256), 256, 0, stream>>>(rp, bsum, N, Etot, cursor);
    k_scatter<<<2048, 256, 0, stream>>>(s32, d32, E, N, cursor, esrc);

    k_cvtW1<<<divup(512 * 128, 256), 256, 0, stream>>>(W1, W1t);
    k_cvtW2<<<divup(128 * 64, 256), 256, 0, stream>>>(W2, W2t);

    k_gemm1<<<divup(N, 128), 256, 0, stream>>>(x, W1t, b1, N, t1, n1);
    k_conv<<<divup(N, 4), 256, 0, stream>>>(t1, n1, rp, esrc, N, nullptr, t2, n2);
    k_conv<<<divup(N, 4), 256, 0, stream>>>(t2, n2, rp, esrc, N, beta2, t1, nullptr);
    k_gemm2<<<divup(N, 128), 256, 0, stream>>>(t1, W2t, b2, N, out);
}

// Round 12
// 395.278 us; speedup vs baseline: 1.1543x; 1.0249x over previous
//
#include <hip/hip_runtime.h>
#include <math.h>

// ---------------------------------------------------------------------------
// AGNN round 12: gemm1 re-tiled for TLP. r7/r8/r10/r11 all pinned at
// 116-121us with Occ 16-17% -> common cause: grid 782 = 3 blocks/CU of WORK.
//  - 64-row tile (grid 1563), 4 waves x 16 rows, W phase = 128k -> LDS 32KB
//    exactly -> 5 blocks/CU resident (~20 waves/CU, 2.5x current)
//  - epilogue in two 32-row passes (sc 16.9KB + pk 8.5KB padded = 25.6KB)
//  - A-stream: verified 1-deep reg-dbuf (r8)
// conv = r10 chunked+pipelined (verified); rest identical to r11.
// ---------------------------------------------------------------------------

static inline int divup(int a, int b) { return (a + b - 1) / b; }

typedef __attribute__((ext_vector_type(8))) short short8;
typedef __attribute__((ext_vector_type(4))) float f32x4;
union U16 { uint4 u; short8 s; };

__device__ __forceinline__ unsigned bf16r(float f) {  // f32 -> bf16 bits, RNE
    unsigned u = __float_as_uint(f);
    return (u + 0x7FFFu + ((u >> 16) & 1u)) >> 16;
}
__device__ __forceinline__ unsigned pack2(float a, float b) {
    return bf16r(a) | (bf16r(b) << 16);
}
__device__ __forceinline__ float bflo(unsigned u) { return __uint_as_float(u << 16); }
__device__ __forceinline__ float bfhi(unsigned u) { return __uint_as_float(u & 0xFFFF0000u); }

// --- edge dtype detect / convert (+histogram fold) -------------------------
__global__ __launch_bounds__(64) void k_detect(const int* __restrict__ raw, int* flag) {
    int t = threadIdx.x;
    int v = raw[2 * t + 1];
    unsigned long long b = __ballot(v != 0);
    if (t == 0) *flag = (b == 0ULL) ? 1 : 0;  // 1 => int64 layout
}

__global__ __launch_bounds__(256) void k_cvt(const int* __restrict__ raw, int E,
                                             const int* __restrict__ flag,
                                             int* __restrict__ s32, int* __restrict__ d32,
                                             int* __restrict__ cnt) {
    int i = blockIdx.x * blockDim.x + threadIdx.x;
    if (i >= E) return;
    int s, d;
    if (*flag) {
        s = raw[2 * (size_t)i];
        d = raw[2 * ((size_t)E + i)];
    } else {
        s = raw[i];
        d = raw[(size_t)E + i];
    }
    s32[i] = s;
    d32[i] = d;
    atomicAdd(&cnt[d], 1);
}

// --- CSR scan (cnt + 1 self-loop per node) ---------------------------------
__global__ __launch_bounds__(1024) void k_scan1(const int* __restrict__ cnt, int N,
                                                int* __restrict__ rp, int* __restrict__ bsum) {
    __shared__ int sm[1024];
    int t = threadIdx.x;
    int i = blockIdx.x * 1024 + t;
    int v = (i < N) ? cnt[i] + 1 : 0;  // +1: self-loop
    sm[t] = v;
    __syncthreads();
#pragma unroll
    for (int off = 1; off < 1024; off <<= 1) {
        int u = (t >= off) ? sm[t - off] : 0;
        __syncthreads();
        sm[t] += u;
        __syncthreads();
    }
    if (i < N) rp[i] = sm[t] - v;  // exclusive
    if (t == 1023) bsum[blockIdx.x] = sm[t];
}

__global__ __launch_bounds__(64) void k_scan2(int* __restrict__ bsum, int nb) {
    if (threadIdx.x == 0) {
        int run = 0;
        for (int i = 0; i < nb; ++i) { int v = bsum[i]; bsum[i] = run; run += v; }
    }
}

__global__ __launch_bounds__(256) void k_scan3(int* __restrict__ rp, const int* __restrict__ bsum,
                                               int N, int Etot, int* __restrict__ cursor) {
    int i = blockIdx.x * blockDim.x + threadIdx.x;
    if (i < N) {
        int v = rp[i] + bsum[i >> 10];
        rp[i] = v;
        cursor[i] = v;
    } else if (i == N) {
        rp[N] = Etot;
    }
}

// --- XCD-partitioned scatter -----------------------------------------------
__global__ __launch_bounds__(256) void k_scatter(const int* __restrict__ s32,
                                                 const int* __restrict__ d32, int E, int N,
                                                 int* __restrict__ cursor,
                                                 int* __restrict__ esrc) {
    int b = blockIdx.x;
    int xcd = b & 7;
    int nstripe = gridDim.x >> 3;
    int stripe = b >> 3;
    int lo = (int)(((long long)xcd * N) >> 3);
    int hi = (int)(((long long)(xcd + 1) * N) >> 3);
    int Etot = E + N;
    for (int e = stripe * 256 + threadIdx.x; e < Etot; e += nstripe * 256) {
        int d = (e < E) ? d32[e] : (e - E);
        if (d < lo || d >= hi) continue;
        int s = (e < E) ? s32[e] : d;
        int pos = atomicAdd(&cursor[d], 1);
        esrc[pos] = s;
    }
}

// --- weight preconvert -----------------------------------------------------
__global__ __launch_bounds__(256) void k_cvtW1(const float* __restrict__ W1,
                                               unsigned short* __restrict__ W1t) {
    int i = blockIdx.x * 256 + threadIdx.x;
    if (i >= 512 * 128) return;
    int k = i >> 7, n = i & 127;
    W1t[n * 512 + k] = (unsigned short)bf16r(W1[i]);
}

__global__ __launch_bounds__(256) void k_cvtW2(const float* __restrict__ W2,
                                               unsigned short* __restrict__ W2t) {
    int i = blockIdx.x * 256 + threadIdx.x;
    if (i >= 128 * 64) return;
    int k = i >> 6, n = i & 63;
    W2t[n * 128 + k] = (unsigned short)bf16r(W2[i]);
}

// --- GEMM1: x_hat1/norm1 = normalize(relu(x @ W1 + b1)) --------------------
// 64-row tile, W-resident in 4 phases of 128k (32KB LDS), A reg-streamed.
#define XSW(c, off) ((off) ^ (((c) & 7) << 4))
__global__ __launch_bounds__(256) void k_gemm1(const float* __restrict__ x,
                                               const unsigned short* __restrict__ W1t,
                                               const float* __restrict__ b1, int N,
                                               unsigned short* __restrict__ xh1,
                                               float* __restrict__ n1) {
    __shared__ __align__(16) unsigned char lds[32768];
    const int tid = threadIdx.x;
    const int lane = tid & 63;
    const int lt = lane & 15, lg = lane >> 4;
    const int w = tid >> 6;
    const int row0 = blockIdx.x * 64;

    // per-lane A row pointer (clamped; rows >= N computed, never stored)
    int arow = row0 + w * 16 + lt;
    if (arow > N - 1) arow = N - 1;
    const float* xb = x + (size_t)arow * 512 + lg * 8;

    f32x4 acc[8];
#pragma unroll
    for (int j = 0; j < 8; ++j) acc[j] = (f32x4){0.f, 0.f, 0.f, 0.f};

    float4 ac[2], an[2];
    ac[0] = ((const float4*)xb)[0];
    ac[1] = ((const float4*)xb)[1];

    for (int ph = 0; ph < 4; ++ph) {
        const int kb = ph * 128;
        __syncthreads();  // prior phase's B-frag reads done
        {
            int c = tid >> 1, h = tid & 1;
            const uint4* wp = (const uint4*)(W1t + c * 512 + kb + h * 64);
            unsigned char* base = lds + c * 256;
#pragma unroll
            for (int i = 0; i < 8; ++i)
                *(uint4*)(base + XSW(c, h * 128 + i * 16)) = wp[i];
        }
        __syncthreads();

#pragma unroll
        for (int ks = 0; ks < 4; ++ks) {
            const int kg = ph * 4 + ks;
            if (kg < 15) {
                an[0] = ((const float4*)(xb + (kg + 1) * 32))[0];
                an[1] = ((const float4*)(xb + (kg + 1) * 32))[1];
            }
            U16 af;
            af.u.x = pack2(ac[0].x, ac[0].y);
            af.u.y = pack2(ac[0].z, ac[0].w);
            af.u.z = pack2(ac[1].x, ac[1].y);
            af.u.w = pack2(ac[1].z, ac[1].w);
#pragma unroll
            for (int cf = 0; cf < 8; ++cf) {
                int col = cf * 16 + lt;
                U16 bf;
                bf.u = *(const uint4*)(lds + col * 256 + XSW(col, ks * 64 + lg * 16));
                acc[cf] = __builtin_amdgcn_mfma_f32_16x16x32_bf16(
                    af.s, bf.s, acc[cf], 0, 0, 0);
            }
            if (kg < 15) {
                ac[0] = an[0];
                ac[1] = an[1];
            }
        }
    }

    // epilogue: two 32-row passes: bias+relu -> sc rows -> norm -> pk -> dense
    float bias[8];
#pragma unroll
    for (int cf = 0; cf < 8; ++cf) bias[cf] = b1[cf * 16 + lt];
    float* sc = (float*)lds;              // 32 rows x 132 f32 = 16896B
    unsigned char* pk = lds + 16896;      // 32 rows x 272B = 8704B
#pragma unroll 1
    for (int p = 0; p < 2; ++p) {
        __syncthreads();
        if ((w >> 1) == p) {
#pragma unroll
            for (int reg = 0; reg < 4; ++reg) {
                int rl = (w & 1) * 16 + lg * 4 + reg;
#pragma unroll
                for (int cf = 0; cf < 8; ++cf)
                    sc[rl * 132 + cf * 16 + lt] =
                        fmaxf(acc[cf][reg] + bias[cf], 0.f);
            }
        }
        __syncthreads();
        {
            int rl = tid >> 3, q = tid & 7;  // 8 threads/row, 16 f32 each
            int gr = row0 + p * 32 + rl;
            const float* rowp = sc + rl * 132 + q * 16;
            float v[16];
#pragma unroll
            for (int i = 0; i < 4; ++i) {
                float4 f = ((const float4*)rowp)[i];
                v[4 * i] = f.x; v[4 * i + 1] = f.y; v[4 * i + 2] = f.z; v[4 * i + 3] = f.w;
            }
            float s2 = 0.f;
#pragma unroll
            for (int i = 0; i < 16; ++i) s2 += v[i] * v[i];
            s2 += __shfl_xor(s2, 1, 64);
            s2 += __shfl_xor(s2, 2, 64);
            s2 += __shfl_xor(s2, 4, 64);
            float nrm = sqrtf(s2);
            float rn = 1.0f / fmaxf(nrm, 1e-12f);
            uint4 o[2];
            unsigned* op = (unsigned*)o;
#pragma unroll
            for (int i = 0; i < 8; ++i)
                op[i] = pack2(v[2 * i] * rn, v[2 * i + 1] * rn);
            uint4* pd = (uint4*)(pk + rl * 272 + q * 32);
            pd[0] = o[0];
            pd[1] = o[1];
            if (q == 0 && gr < N) n1[gr] = nrm;
        }
        __syncthreads();
#pragma unroll
        for (int j = 0; j < 2; ++j) {
            int boff = j * 4096 + tid * 16;
            int r = boff >> 8;
            int inner = boff & 255;
            int gr = row0 + p * 32 + r;
            if (gr < N)
                *(uint4*)((unsigned char*)xh1 + (size_t)gr * 256 + inner) =
                    *(const uint4*)(pk + r * 272 + inner);
        }
    }
}

// --- AGNN conv: 16x4 geometry, chunked idx/norm batch + 2-deep row pipe ----
__global__ __launch_bounds__(256) void k_conv(const unsigned short* __restrict__ xh,
                                              const float* __restrict__ nrmt,
                                              const int* __restrict__ rp,
                                              const int* __restrict__ esrc, int N,
                                              const float* __restrict__ betap,
                                              unsigned short* __restrict__ outh,
                                              float* __restrict__ outn) {
    int node = (blockIdx.x * blockDim.x + threadIdx.x) >> 6;
    if (node >= N) return;
    int lane = threadIdx.x & 63;
    int t = lane & 15, g = lane >> 4;
    float beta = betap ? *betap : 1.0f;

    uint4 hdu = *(const uint4*)&xh[(size_t)node * 128 + 8 * t];
    float hd[8];
    hd[0] = bflo(hdu.x); hd[1] = bfhi(hdu.x);
    hd[2] = bflo(hdu.y); hd[3] = bfhi(hdu.y);
    hd[4] = bflo(hdu.z); hd[5] = bfhi(hdu.z);
    hd[6] = bflo(hdu.w); hd[7] = bfhi(hdu.w);

    int e0 = rp[node], e1 = rp[node + 1];
    float acc[8] = {0.f, 0.f, 0.f, 0.f, 0.f, 0.f, 0.f, 0.f};
    float ssum = 0.f;

    for (int cs = e0; cs < e1; cs += 64) {
        int el = cs + lane;
        int sidx = esrc[(el < e1) ? el : e0];
        float nsl = nrmt[sidx];
        int R = e1 - cs;
        if (R > 64) R = 64;
        int nr = (R + 3) >> 2;

        int sA = __shfl(sidx, g, 64);
        float nsA = __shfl(nsl, g, 64);
        uint4 rowA = *(const uint4*)&xh[(size_t)sA * 128 + 8 * t];

        for (int r = 0; r < nr; ++r) {
            const bool hasNext = (r + 1) < nr;
            uint4 rowB;
            float nsB = 0.f;
            if (hasNext) {
                int sB = __shfl(sidx, 4 * (r + 1) + g, 64);
                nsB = __shfl(nsl, 4 * (r + 1) + g, 64);
                rowB = *(const uint4*)&xh[(size_t)sB * 128 + 8 * t];
            }
            float v[8];
            v[0] = bflo(rowA.x); v[1] = bfhi(rowA.x);
            v[2] = bflo(rowA.y); v[3] = bfhi(rowA.y);
            v[4] = bflo(rowA.z); v[5] = bfhi(rowA.z);
            v[6] = bflo(rowA.w); v[7] = bfhi(rowA.w);
            float p = 0.f;
#pragma unroll
            for (int j = 0; j < 8; ++j) p += v[j] * hd[j];
            p += __shfl_xor(p, 1, 64);
            p += __shfl_xor(p, 2, 64);
            p += __shfl_xor(p, 4, 64);
            p += __shfl_xor(p, 8, 64);
            int e = cs + 4 * r + g;
            float w = (e < e1) ? __expf(p * beta) : 0.f;
            float wn = w * nsA;
            ssum += w;
#pragma unroll
            for (int j = 0; j < 8; ++j) acc[j] += wn * v[j];
            if (hasNext) {
                rowA = rowB;
                nsA = nsB;
            }
        }
    }
#pragma unroll
    for (int j = 0; j < 8; ++j) {
        acc[j] += __shfl_xor(acc[j], 16, 64);
        acc[j] += __shfl_xor(acc[j], 32, 64);
    }
    ssum += __shfl_xor(ssum, 16, 64);
    ssum += __shfl_xor(ssum, 32, 64);
    float r = 1.0f / ssum;

    if (outn == nullptr) {
        if (g == 0) {
            uint4 q;
            q.x = pack2(acc[0] * r, acc[1] * r);
            q.y = pack2(acc[2] * r, acc[3] * r);
            q.z = pack2(acc[4] * r, acc[5] * r);
            q.w = pack2(acc[6] * r, acc[7] * r);
            *(uint4*)&outh[(size_t)node * 128 + 8 * t] = q;
        }
    } else {
        float o[8];
        float s2 = 0.f;
#pragma unroll
        for (int j = 0; j < 8; ++j) { o[j] = acc[j] * r; s2 += o[j] * o[j]; }
        s2 += __shfl_xor(s2, 1, 64);
        s2 += __shfl_xor(s2, 2, 64);
        s2 += __shfl_xor(s2, 4, 64);
        s2 += __shfl_xor(s2, 8, 64);
        float nn = sqrtf(s2);
        float rn = 1.0f / fmaxf(nn, 1e-12f);
        if (g == 0) {
            uint4 q;
            q.x = pack2(o[0] * rn, o[1] * rn);
            q.y = pack2(o[2] * rn, o[3] * rn);
            q.z = pack2(o[4] * rn, o[5] * rn);
            q.w = pack2(o[6] * rn, o[7] * rn);
            *(uint4*)&outh[(size_t)node * 128 + 8 * t] = q;
            if (t == 0) outn[node] = nn;
        }
    }
}

// --- GEMM2 (MFMA) + fused log_softmax --------------------------------------
#define G2_ASTRIDE 272
__global__ __launch_bounds__(256) void k_gemm2(const unsigned short* __restrict__ h,
                                               const unsigned short* __restrict__ W2t,
                                               const float* __restrict__ b2, int N,
                                               float* __restrict__ out) {
    __shared__ __align__(16) unsigned char As[128 * G2_ASTRIDE];
    __shared__ __align__(16) unsigned char Bs[64 * G2_ASTRIDE];
    const int tid = threadIdx.x;
    const int lane = tid & 63;
    const int lt = lane & 15, lg = lane >> 4;
    const int wid = tid >> 6;
    const int row0 = blockIdx.x * 128;

    {
        int arow = tid >> 1, ahalf = tid & 1;
        const uint4* src = (const uint4*)(h + (size_t)(row0 + arow) * 128 + ahalf * 64);
        unsigned char* ab = As + arow * G2_ASTRIDE + ahalf * 128;
#pragma unroll
        for (int i = 0; i < 8; ++i) ((uint4*)ab)[i] = src[i];
        int brow = tid >> 2, bq = tid & 3;
        const uint4* bs = (const uint4*)(W2t + (size_t)brow * 128 + bq * 32);
        unsigned char* bb = Bs + brow * G2_ASTRIDE + bq * 64;
#pragma unroll
        for (int i = 0; i < 4; ++i) ((uint4*)bb)[i] = bs[i];
    }
    __syncthreads();

    f32x4 acc[2][4];
#pragma unroll
    for (int i = 0; i < 2; ++i)
#pragma unroll
        for (int j = 0; j < 4; ++j) acc[i][j] = (f32x4){0.f, 0.f, 0.f, 0.f};

#pragma unroll
    for (int sub = 0; sub < 4; ++sub) {
        U16 af[2], bf[4];
#pragma unroll
        for (int mi = 0; mi < 2; ++mi)
            af[mi].u = *(const uint4*)(As + (wid * 32 + mi * 16 + lt) * G2_ASTRIDE + sub * 64 + lg * 16);
#pragma unroll
        for (int ni = 0; ni < 4; ++ni)
            bf[ni].u = *(const uint4*)(Bs + (ni * 16 + lt) * G2_ASTRIDE + sub * 64 + lg * 16);
#pragma unroll
        for (int mi = 0; mi < 2; ++mi)
#pragma unroll
            for (int ni = 0; ni < 4; ++ni)
                acc[mi][ni] = __builtin_amdgcn_mfma_f32_16x16x32_bf16(
                    af[mi].s, bf[ni].s, acc[mi][ni], 0, 0, 0);
    }

    float bias[4];
#pragma unroll
    for (int ni = 0; ni < 4; ++ni) bias[ni] = b2[ni * 16 + lt];

#pragma unroll
    for (int mi = 0; mi < 2; ++mi) {
#pragma unroll
        for (int reg = 0; reg < 4; ++reg) {
            int row = row0 + wid * 32 + mi * 16 + lg * 4 + reg;
            if (row < N) {
                float v[4];
#pragma unroll
                for (int ni = 0; ni < 4; ++ni) v[ni] = acc[mi][ni][reg] + bias[ni];
                float m = fmaxf(fmaxf(v[0], v[1]), fmaxf(v[2], v[3]));
                m = fmaxf(m, __shfl_xor(m, 1, 64));
                m = fmaxf(m, __shfl_xor(m, 2, 64));
                m = fmaxf(m, __shfl_xor(m, 4, 64));
                m = fmaxf(m, __shfl_xor(m, 8, 64));
                float s = __expf(v[0] - m) + __expf(v[1] - m) +
                          __expf(v[2] - m) + __expf(v[3] - m);
                s += __shfl_xor(s, 1, 64);
                s += __shfl_xor(s, 2, 64);
                s += __shfl_xor(s, 4, 64);
                s += __shfl_xor(s, 8, 64);
                float lg2 = logf(s);
#pragma unroll
                for (int ni = 0; ni < 4; ++ni)
                    out[(size_t)row * 64 + ni * 16 + lt] = v[ni] - m - lg2;
            }
        }
    }
}

// ---------------------------------------------------------------------------
extern "C" void kernel_launch(void* const* d_in, const int* in_sizes, int n_in,
                              void* d_out, int out_size, void* d_ws, size_t ws_size,
                              hipStream_t stream) {
    const float* x     = (const float*)d_in[0];
    const int*   ei    = (const int*)d_in[1];
    const float* W1    = (const float*)d_in[2];
    const float* b1    = (const float*)d_in[3];
    const float* beta2 = (const float*)d_in[4];
    const float* W2    = (const float*)d_in[5];
    const float* b2    = (const float*)d_in[6];
    float* out = (float*)d_out;

    const int N = in_sizes[0] / 512;
    const int E = in_sizes[1] / 2;
    const int Etot = E + N;

    char* ws = (char*)d_ws;
    size_t off = 0;
    auto alloc = [&](size_t bytes) -> void* {
        void* p = ws + off;
        off = (off + bytes + 511) & ~(size_t)511;
        return p;
    };
    unsigned short* t1 = (unsigned short*)alloc((size_t)N * 128 * 2);  // x_hat1 / h3
    unsigned short* t2 = (unsigned short*)alloc((size_t)N * 128 * 2);  // x_hat2
    float* n1   = (float*)alloc((size_t)N * 4);
    float* n2   = (float*)alloc((size_t)N * 4);
    int* cnt    = (int*)alloc((size_t)N * 4);
    int* rp     = (int*)alloc((size_t)(N + 1) * 4);
    int* cursor = (int*)alloc((size_t)N * 4);
    int* bsum   = (int*)alloc(4096);
    int* flag   = (int*)alloc(512);
    unsigned short* W1t = (unsigned short*)alloc(512 * 128 * 2);
    unsigned short* W2t = (unsigned short*)alloc(128 * 64 * 2);
    int* s32    = (int*)alloc((size_t)E * 4);
    int* d32    = (int*)alloc((size_t)E * 4);
    int* esrc   = (int*)alloc((size_t)Etot * 4);
    (void)ws_size; (void)n_in; (void)out_size;

    (void)hipMemsetAsync(cnt, 0, (size_t)N * 4, stream);

    k_detect<<<1, 64, 0, stream>>>(ei, flag);
    k_cvt<<<divup(E, 256), 256, 0, stream>>>(ei, E, flag, s32, d32, cnt);
    int nb = divup(N, 1024);
    k_scan1<<<nb, 1024, 0, stream>>>(cnt, N, rp, bsum);
    k_scan2<<<1, 64, 0, stream>>>(bsum, nb);
    k_scan3<<<divup(N + 1, 256), 256, 0, stream>>>(rp, bsum, N, Etot, cursor);
    k_scatter<<<2048, 256, 0, stream>>>(s32, d32, E, N, cursor, esrc);

    k_cvtW1<<<divup(512 * 128, 256), 256, 0, stream>>>(W1, W1t);
    k_cvtW2<<<divup(128 * 64, 256), 256, 0, stream>>>(W2, W2t);

    k_gemm1<<<divup(N, 64), 256, 0, stream>>>(x, W1t, b1, N, t1, n1);
    k_conv<<<divup(N, 4), 256, 0, stream>>>(t1, n1, rp, esrc, N, nullptr, t2, n2);
    k_conv<<<divup(N, 4), 256, 0, stream>>>(t2, n2, rp, esrc, N, beta2, t1, nullptr);
    k_gemm2<<<divup(N, 128), 256, 0, stream>>>(t1, W2t, b2, N, out);
}